// Round 24
// baseline (585.164 us; speedup 1.0000x reference)
//
#include <hip/hip_runtime.h>
#include <math.h>

// ---------------- problem constants ----------------
constexpr int    BB      = 8;
constexpr int    NN      = 16384;
constexpr size_t SZ_XQ_ST = (size_t)BB * 128 * NN;
constexpr size_t SZ_XF_ST = (size_t)BB * 64 * NN;

// float-slot offsets in ws
constexpr size_t OFF_XQ   = 0;                          // xqb bf16 [2][8][16384][128]
constexpr size_t OFF_XT   = 16777216;                   // Xt bf16 [2][8][16384][64]
constexpr size_t OFF_XF   = 33554432;                   // t-field bf16 [8][64][16384] (attn st=0); Wt staging early
constexpr size_t OFF_XG   = OFF_XF + 8388608;           // tanh-only bf16 [8][16384][64] channel-last
constexpr size_t OFF_POOL = OFF_XF + 2 * SZ_XF_ST;      // pooled feats f32 (788,480)
constexpr size_t OFF_XK   = OFF_POOL + 788480;          // xkb bf16 [48][112][128]
constexpr size_t OFF_XV   = OFF_XK + 344064;            // xv f32 [48][128][112]
constexpr size_t OFF_MT   = OFF_XV + 688128;            // MTb bf16 [48][64][128]
constexpr size_t OFF_W    = OFF_MT + 393216;            // W f32 [2][3][64][192]
constexpr size_t OFF_AT   = OFF_W + 73728;              // ATb bf16 [2][64][64]
constexpr size_t OFF_WT   = OFF_AT + 4096;              // t/p/g w bf16 [3][64][64] row-major [o][c]
constexpr size_t OFF_ATTC = OFF_WT + 12288;             // [8][8][3] raw sums
constexpr size_t OFF_MV   = OFF_ATTC + 192;             // [8][8][2]
constexpr size_t OFF_PART = OFF_MV + 128;               // attc partials [192][512]
constexpr size_t OFF_PART2= OFF_PART + 98304;           // stats partials [64][8][2]

#define A0SQ 0.9998000199986667f
#define A1SQ 1.9996000399973335e-4f
#define A2SQ 1.9996000399973334e-8f

typedef __attribute__((ext_vector_type(8))) short bf16x8;
typedef __attribute__((ext_vector_type(4))) float f32x4;

__device__ inline ushort f2bf(float f) {
    uint u = __float_as_uint(f);
    return (ushort)((u + 0x7fffu + ((u >> 16) & 1u)) >> 16);
}
__device__ inline float bf2f(ushort u) { return __uint_as_float((uint)u << 16); }
// RNE pair pack (proven bits; do NOT use v_cvt_pk_bf16_f32 — RTZ, caused R9 fail)
__device__ inline uint pk2bf(float lo, float hi) {
    return (uint)f2bf(lo) | ((uint)f2bf(hi) << 16);
}

// ---------------- input transpose: f32 [64][128][128] -> bf16 [y][x][64] ----------------
__global__ __launch_bounds__(256) void k_xt(const float* __restrict__ in0, const float* __restrict__ in1,
                                            ushort* __restrict__ xt0, ushort* __restrict__ xt1) {
    __shared__ float L[64 * 130];
    const int y = blockIdx.x, b = blockIdx.y, tid = threadIdx.x;
    const float* in = blockIdx.z ? in1 : in0;
    ushort* xt = blockIdx.z ? xt1 : xt0;
    const float* ib = in + (((size_t)b * 64) << 14) + (y << 7);
    for (int r = 0; r < 32; ++r) {
        int idx = tid + (r << 8); int ch = idx >> 7; int x = idx & 127;
        L[ch * 130 + x] = ib[((size_t)ch << 14) + x];
    }
    __syncthreads();
    const int x = tid >> 1, seg = tid & 1;
    ushort* ob = xt + ((size_t)(b * 128 + y) * 128 + x) * 64 + seg * 32;
    uint pk[16];
#pragma unroll
    for (int c = 0; c < 16; ++c)
        pk[c] = pk2bf(L[(seg * 32 + 2 * c) * 130 + x], L[(seg * 32 + 2 * c + 1) * 130 + x]);
    uint4* o4 = (uint4*)ob;
#pragma unroll
    for (int c = 0; c < 4; ++c) o4[c] = make_uint4(pk[4 * c], pk[4 * c + 1], pk[4 * c + 2], pk[4 * c + 3]);
}

// ---------------- weight re-layout: f32 [oc][ic][3][3] -> bf16 [t][oc][ic] ----------------
__global__ __launch_bounds__(256) void k_wt(const float* __restrict__ w1, const float* __restrict__ w2,
                                            ushort* __restrict__ wt1, ushort* __restrict__ wt2) {
    int id = blockIdx.x * 256 + threadIdx.x;
    if (id >= 147456) return;
    int cs = id / 73728; int rem = id - cs * 73728;
    int t = rem >> 13; int oc = (rem >> 6) & 127; int ic = rem & 63;
    const float* w = cs ? w2 : w1;
    (cs ? wt2 : wt1)[rem] = f2bf(w[((size_t)(oc * 64 + ic)) * 9 + t]);
}

// ---------------- conv 3x3 SAME 64->128 bf16 MFMA v2 (proven best) ----------------
__global__ __launch_bounds__(256, 2) void k_convm2(const ushort* __restrict__ Xt0, const ushort* __restrict__ Xt1,
                                                   const ushort* __restrict__ Wt0, const ushort* __restrict__ Wt1,
                                                   ushort* __restrict__ out_base) {
    __shared__ ushort smem[3 * 130 * 72];
    const int tid = threadIdx.x;
    const int y = blockIdx.x, b = blockIdx.y;
    const ushort* Xt = blockIdx.z ? Xt1 : Xt0;
    const ushort* Wt = blockIdx.z ? Wt1 : Wt0;
    ushort* out = out_base + (size_t)blockIdx.z * 16777216;
    const int l = tid & 63;
    const int wv = __builtin_amdgcn_readfirstlane(tid >> 6);
    const int lr = l & 15;
    const int q = l >> 4;

    for (int slot = tid; slot < 390; slot += 256) {
        int dy = slot / 130, xx = slot - dy * 130;
        int row = y + dy - 1, sx = xx - 1;
        bool v = (row >= 0) & (row < 128) & (sx >= 0) & (sx < 128);
        const uint4* s = (const uint4*)(Xt + (((size_t)(b * 128 + row) * 128 + sx) * 64));
        uint4* d = (uint4*)(smem + (size_t)slot * 72);
        uint4 z = make_uint4(0, 0, 0, 0);
#pragma unroll
        for (int j = 0; j < 8; ++j) d[j] = v ? s[j] : z;
    }
    __syncthreads();

    f32x4 acc[2][8];
#pragma unroll
    for (int f = 0; f < 2; ++f)
#pragma unroll
        for (int g = 0; g < 8; ++g)
#pragma unroll
            for (int r = 0; r < 4; ++r) acc[f][g][r] = 0.f;

#pragma unroll
    for (int t = 0; t < 9; ++t) {
        const int dy = t / 3, dx = t - dy * 3;
#pragma unroll
        for (int h = 0; h < 2; ++h) {
            const int ko = h * 32 + q * 8;
            bf16x8 a0 = *(const bf16x8*)(Wt + ((size_t)(t * 128 + wv * 32 + lr) * 64 + ko));
            bf16x8 a1 = *(const bf16x8*)(Wt + ((size_t)(t * 128 + wv * 32 + 16 + lr) * 64 + ko));
#pragma unroll
            for (int g = 0; g < 8; ++g) {
                bf16x8 bb = *(const bf16x8*)(smem + (size_t)(dy * 130 + g * 16 + lr + dx) * 72 + ko);
                acc[0][g] = __builtin_amdgcn_mfma_f32_16x16x32_bf16(a0, bb, acc[0][g], 0, 0, 0);
                acc[1][g] = __builtin_amdgcn_mfma_f32_16x16x32_bf16(a1, bb, acc[1][g], 0, 0, 0);
            }
        }
    }
    __syncthreads();
    uint* T = (uint*)smem;
#pragma unroll
    for (int f = 0; f < 2; ++f)
#pragma unroll
        for (int g = 0; g < 8; ++g) {
            int dw = (g * 16 + lr) * 68 + wv * 16 + f * 8 + q * 2;
            T[dw] = pk2bf(acc[f][g][0], acc[f][g][1]);
            T[dw + 1] = pk2bf(acc[f][g][2], acc[f][g][3]);
        }
    __syncthreads();
    const int x = tid >> 1, sg = tid & 1;
    ushort* ob = out + ((size_t)(b * 128 + y) * 128 + x) * 128 + sg * 64;
    const uint* src = &T[x * 68 + sg * 32];
#pragma unroll
    for (int j = 0; j < 8; ++j) {
        uint4 vv = *(const uint4*)(src + 4 * j);
        *(uint4*)(ob + j * 8) = vv;
    }
}

// ---------------- pyramid pooling v2: plane-packed ----------------
struct PoolPtrs { const float* src[6]; };

__global__ __launch_bounds__(256) void k_pool2(PoolPtrs pp, float* __restrict__ ws) {
    extern __shared__ float P[];
    const int blk = blockIdx.x;
    const int tid = threadIdx.x;
    if (blk < 1024) {
        const int tI = (blk < 512) ? 0 : 3;
        const int local = (blk < 512) ? blk : blk - 512;
        const size_t toff = (tI == 0) ? 0 : 394240;
        const int h = 128, stride = 129;
        const float* img = pp.src[tI] + (size_t)local * h * h;
        for (int f = tid; f < h * h; f += 256) {
            int r = f >> 7; int cc = f & 127;
            P[r * stride + cc] = img[f];
        }
        __syncthreads();
        if (tid < h) {
            float cur = 0.f; const int rb = tid * stride;
            for (int cc = 0; cc < h; ++cc) { cur += P[rb + cc]; P[rb + cc] = cur; }
        }
        __syncthreads();
        if (tid < h) {
            float cur = 0.f;
            for (int r = 0; r < h; ++r) { int a = r * stride + tid; cur += P[a]; P[a] = cur; }
        }
        __syncthreads();
        if (tid < 110) {
            int s, off2;
            if (tid == 0)      { s = 1; off2 = 0; }
            else if (tid < 10) { s = 3; off2 = 1; }
            else if (tid < 46) { s = 6; off2 = 10; }
            else               { s = 8; off2 = 46; }
            int r = tid - off2; int j = r / s; int q = r - j * s;
            const int n = h + 2;
            int ra = (j * n) / s,       rb2 = ((j + 1) * n + s - 1) / s;
            int ca = (q * n) / s,       cb2 = ((q + 1) * n + s - 1) / s;
            float area = (float)((rb2 - ra) * (cb2 - ca));
            int r0 = ra - 1; if (r0 < 0) r0 = 0;  int r1 = rb2 - 1; if (r1 > h) r1 = h;
            int c0 = ca - 1; if (c0 < 0) c0 = 0;  int c1 = cb2 - 1; if (c1 > h) c1 = h;
            float ssum = 0.f;
            if (r1 > r0 && c1 > c0) {
                int ri = r1 - 1, rj = r0 - 1, ci = c1 - 1, cj = c0 - 1;
                float f11 = P[ri * stride + ci];
                float f01 = (rj < 0) ? 0.f : P[rj * stride + ci];
                float f10 = (cj < 0) ? 0.f : P[ri * stride + cj];
                float f00 = (rj < 0 || cj < 0) ? 0.f : P[rj * stride + cj];
                ssum = f11 - f01 - f10 + f00;
            }
            ws[OFF_POOL + toff + (size_t)local * 110 + tid] = ssum / area;
        }
    } else {
        int h, hs, tI, local0;
        if (blk < 1536) {
            h = 64; hs = 6;
            if (blk < 1280) { tI = 1; local0 = (blk - 1024) * 4; }
            else            { tI = 4; local0 = (blk - 1280) * 4; }
        } else {
            h = 32; hs = 5;
            if (blk < 1792) { tI = 2; local0 = (blk - 1536) * 8; }
            else            { tI = 5; local0 = (blk - 1792) * 8; }
        }
        const size_t toff = (tI == 1) ? 56320 : (tI == 4) ? 450560 : (tI == 2) ? 168960 : 563200;
        const int lg = tid >> hs;
        const int lr = tid & (h - 1);
        const int stride = h + 1;
        float* Pb = P + (size_t)lg * h * stride;
        const float* img = pp.src[tI] + (size_t)(local0 + lg) * h * h;
        for (int f = lr; f < h * h; f += h) {
            int r = f >> hs; int cc = f & (h - 1);
            Pb[r * stride + cc] = img[f];
        }
        __syncthreads();
        {
            float cur = 0.f; const int rb = lr * stride;
            for (int cc = 0; cc < h; ++cc) { cur += Pb[rb + cc]; Pb[rb + cc] = cur; }
        }
        __syncthreads();
        {
            float cur = 0.f;
            for (int r = 0; r < h; ++r) { int a = r * stride + lr; cur += Pb[a]; Pb[a] = cur; }
        }
        __syncthreads();
        for (int t = lr; t < 110; t += h) {
            int s, off2;
            if (t == 0)      { s = 1; off2 = 0; }
            else if (t < 10) { s = 3; off2 = 1; }
            else if (t < 46) { s = 6; off2 = 10; }
            else             { s = 8; off2 = 46; }
            int r = t - off2; int j = r / s; int q = r - j * s;
            const int n = h + 2;
            int ra = (j * n) / s,       rb2 = ((j + 1) * n + s - 1) / s;
            int ca = (q * n) / s,       cb2 = ((q + 1) * n + s - 1) / s;
            float area = (float)((rb2 - ra) * (cb2 - ca));
            int r0 = ra - 1; if (r0 < 0) r0 = 0;  int r1 = rb2 - 1; if (r1 > h) r1 = h;
            int c0 = ca - 1; if (c0 < 0) c0 = 0;  int c1 = cb2 - 1; if (c1 > h) c1 = h;
            float ssum = 0.f;
            if (r1 > r0 && c1 > c0) {
                int ri = r1 - 1, rj = r0 - 1, ci = c1 - 1, cj = c0 - 1;
                float f11 = Pb[ri * stride + ci];
                float f01 = (rj < 0) ? 0.f : Pb[rj * stride + ci];
                float f10 = (cj < 0) ? 0.f : Pb[ri * stride + cj];
                float f00 = (rj < 0 || cj < 0) ? 0.f : Pb[rj * stride + cj];
                ssum = f11 - f01 - f10 + f00;
            }
            ws[OFF_POOL + toff + (size_t)(local0 + lg) * 110 + t] = ssum / area;
        }
    }
}

// ---------------- small weight precomputes ----------------
__global__ __launch_bounds__(256) void k_pkw(const float* __restrict__ f1, const float* __restrict__ f2,
                                             const float* __restrict__ m1, const float* __restrict__ m2,
                                             const float* __restrict__ tw, const float* __restrict__ pw,
                                             const float* __restrict__ gw, float* __restrict__ ws) {
    int id = blockIdx.x * 256 + threadIdx.x;
    if (id < 73728) {
        int c = id % 192; int t = id / 192; int o = t & 63; int t2 = t >> 6; int i = t2 % 3; int st = t2 / 3;
        const float* fu = st ? f2 : f1; const float* ma = st ? m2 : m1;
        float s = 0.f;
        for (int k = 0; k < 64; ++k) s = fmaf(fu[o * 192 + i * 64 + k], ma[k * 192 + c], s);
        ws[OFF_W + id] = s;
    } else if (id < 81920) {
        int x = id - 73728; int o = x & 63; int c = (x >> 6) & 63; int st = x >> 12;
        const float* fu = st ? f2 : f1; const float* ma = st ? m2 : m1;
        float s = 0.f;
        for (int k = 0; k < 192; ++k) s = fmaf(fu[o * 192 + k], ma[(k & 63) * 192 + c], s);
        ((ushort*)(ws + OFF_AT))[(size_t)st * 4096 + o * 64 + c] = f2bf(s);
    } else if (id < 94208) {
        int x = id - 81920; int c = x & 63; int o = (x >> 6) & 63; int f = x >> 12;
        const float* src = (f == 0) ? tw : ((f == 1) ? pw : gw);
        ((ushort*)(ws + OFF_WT))[(size_t)f * 4096 + o * 64 + c] = f2bf(src[o * 64 + c]);
    }
}

// ---------------- xk (bf16 [p][c]) / xv (f32 [c][p]) from pooled features ----------------
struct KvPtrs { const float* k1[3]; const float* k2[3]; const float* v1[3]; const float* v2[3]; };

__global__ __launch_bounds__(256) void k_xkxv(KvPtrs kp, float* __restrict__ ws) {
    int id = blockIdx.x * 256 + threadIdx.x;
    int isV = 0;
    if (id >= 688128) { isV = 1; id -= 688128; }
    int p = id % 112; int t1 = id / 112; int C = t1 & 127; int t2 = t1 >> 7;
    int b = t2 & 7; int t3 = t2 >> 3; int i = t3 % 3; int st = t3 / 3;
    const int ci = 64 << i;
    size_t poff = (size_t)st * 394240 + (i >= 1 ? 56320 : 0) + (i >= 2 ? 112640 : 0);
    const float* kw = isV ? (st ? kp.v2[i] : kp.v1[i]) : (st ? kp.k2[i] : kp.k1[i]);
    float s = 0.f;
    if (p < 110) {
        const float* pl = ws + OFF_POOL + poff + (size_t)b * ci * 110 + p;
        for (int ic = 0; ic < ci; ++ic) s = fmaf(kw[C * ci + ic], pl[(size_t)ic * 110], s);
    }
    if (isV) ws[OFF_XV + id] = s;
    else     ((ushort*)(ws + OFF_XK))[(size_t)t2 * 14336 + p * 128 + C] = f2bf(s);
}

// ---------------- MTb bf16 [t2][o][p(128, zero-pad)] ----------------
__global__ __launch_bounds__(256) void k_mt(float* __restrict__ ws) {
    int id = blockIdx.x * 256 + threadIdx.x;
    int p = id & 127; int o = (id >> 7) & 63; int t2 = id >> 13;
    int sti = t2 >> 3;
    float s = 0.f;
    if (p < 110) {
        const float* Wrow = ws + OFF_W + ((size_t)sti * 64 + o) * 192 + 64;
        const float* xv = ws + OFF_XV + (size_t)t2 * 128 * 112 + p;
        for (int r = 0; r < 128; ++r) s = fmaf(Wrow[r], xv[(size_t)r * 112], s);
    }
    ((ushort*)(ws + OFF_MT))[id] = f2bf(s);
}

// ---------------- fused MFMA attention v10: xks/pbuf aliased -> 4 blocks/CU ----------------
__global__ __launch_bounds__(256, 4) void k_attn10(float* __restrict__ ws,
                                                   const float* __restrict__ g_in,
                                                   const float* __restrict__ c_in) {
    __shared__ uint ubuf[128 * 68];                     // 34,816 B union: xk stage (S phase) / P+xf tile (PV phase)
    uint* pbuf = ubuf;
    ushort* xks = (ushort*)ubuf;                        // same 68-dword row pitch for both views
    const int tid = threadIdx.x;
    const int w = __builtin_amdgcn_readfirstlane(tid >> 6);
    const int l = tid & 63;
    const int lr = l & 15;
    const int g4 = l >> 4;
    const int n0 = blockIdx.x << 7;
    const int b = blockIdx.y;
    const int st = blockIdx.z;

    const ushort* xqb = (const ushort*)(ws + OFF_XQ);
    const ushort* xkb = (const ushort*)(ws + OFF_XK);
    const ushort* mtb = (const ushort*)(ws + OFF_MT);
    const ushort* atb = (const ushort*)(ws + OFF_AT) + (size_t)st * 4096;
    const ushort* xt  = (const ushort*)(ws + OFF_XT) + (size_t)st * 8388608 + ((size_t)b << 14) * 64;

    const int ng0 = n0 + (2 * w + 0) * 16 + lr;
    const int ng1 = n0 + (2 * w + 1) * 16 + lr;
    const int row0 = w * 32 + lr;
    const int row1 = w * 32 + 16 + lr;
    const int padrow = w * 32 + (l >> 1);
    const int padcol = 56 + ((l & 1) << 2);

    bf16x8 bq[2][4];
    {
        const ushort* p0 = xqb + ((size_t)(st * 8 + b) * 16384 + ng0) * 128 + g4 * 8;
        const ushort* p1 = xqb + ((size_t)(st * 8 + b) * 16384 + ng1) * 128 + g4 * 8;
#pragma unroll
        for (int kk = 0; kk < 4; ++kk) { bq[0][kk] = *(const bf16x8*)(p0 + kk * 32); bq[1][kk] = *(const bf16x8*)(p1 + kk * 32); }
    }

    f32x4 pacc[4][2];
#pragma unroll
    for (int m = 0; m < 4; ++m)
#pragma unroll
        for (int nt = 0; nt < 2; ++nt)
#pragma unroll
            for (int r = 0; r < 4; ++r) pacc[m][nt][r] = 0.f;

    // residual-matrix term A(64x64) @ in
#pragma unroll
    for (int kk = 0; kk < 2; ++kk) {
        bf16x8 bi0 = *(const bf16x8*)(xt + (size_t)ng0 * 64 + kk * 32 + g4 * 8);
        bf16x8 bi1 = *(const bf16x8*)(xt + (size_t)ng1 * 64 + kk * 32 + g4 * 8);
#pragma unroll
        for (int m = 0; m < 4; ++m) {
            bf16x8 a = *(const bf16x8*)(atb + (m * 16 + lr) * 64 + kk * 32 + g4 * 8);
            pacc[m][0] = __builtin_amdgcn_mfma_f32_16x16x32_bf16(a, bi0, pacc[m][0], 0, 0, 0);
            pacc[m][1] = __builtin_amdgcn_mfma_f32_16x16x32_bf16(a, bi1, pacc[m][1], 0, 0, 0);
        }
    }

#pragma unroll 1
    for (int i = 0; i < 3; ++i) {
        // cooperative stage of xk[i] into union LDS (prior PV must be done)
        if (i > 0) __syncthreads();
        {
            const ushort* src = xkb + (size_t)((st * 3 + i) * 8 + b) * 14336;
#pragma unroll
            for (int s2 = 0; s2 < 7; ++s2) {
                int idx = (s2 * 256 + tid) * 8;         // ushort index, 1792 uint4 total
                int row = idx >> 7; int col = idx & 127;
                *(uint4*)(xks + row * 136 + col) = *(const uint4*)(src + idx);
            }
        }
        __syncthreads();

        const ushort* mt_p = mtb + (size_t)((st * 3 + i) * 8 + b) * 8192 + (size_t)lr * 128 + g4 * 8;
        f32x4 sacc[7][2];
#pragma unroll
        for (int m = 0; m < 7; ++m)
#pragma unroll
            for (int nt = 0; nt < 2; ++nt)
#pragma unroll
                for (int r = 0; r < 4; ++r) sacc[m][nt][r] = 0.f;
        // S = xk^T @ xq from LDS
        __builtin_amdgcn_s_setprio(1);
#pragma unroll
        for (int kk = 0; kk < 4; ++kk) {
#pragma unroll
            for (int m = 0; m < 7; ++m) {
                bf16x8 a = *(const bf16x8*)(xks + (m * 16 + lr) * 136 + kk * 32 + g4 * 8);
                sacc[m][0] = __builtin_amdgcn_mfma_f32_16x16x32_bf16(a, bq[0][kk], sacc[m][0], 0, 0, 0);
                sacc[m][1] = __builtin_amdgcn_mfma_f32_16x16x32_bf16(a, bq[1][kk], sacc[m][1], 0, 0, 0);
            }
        }
        __builtin_amdgcn_s_setprio(0);
        // prefetch PV kk=0 A-fragments before the barrier (global, latency overlaps barrier wait)
        bf16x8 mc[4], mn[4];
#pragma unroll
        for (int m = 0; m < 4; ++m) mc[m] = *(const bf16x8*)(mt_p + (size_t)(m * 16) * 128);
        // all waves done reading xks before P overwrites the union
        __syncthreads();
        // re-zero p=112..127 pad in this wave's rows (staging clobbered it)
        *(uint4*)&pbuf[padrow * 68 + padcol] = make_uint4(0, 0, 0, 0);
        // in-register softmax over p for both nt, mask p>=110, clip +-64
#pragma unroll
        for (int nt = 0; nt < 2; ++nt) {
            float mx = -3.0e38f;
#pragma unroll
            for (int m = 0; m < 7; ++m)
#pragma unroll
                for (int r = 0; r < 4; ++r) {
                    int p = m * 16 + g4 * 4 + r;
                    float s = fminf(fmaxf(sacc[m][nt][r], -64.f), 64.f);
                    if (p >= 110) s = -3.0e38f;
                    sacc[m][nt][r] = s;
                    mx = fmaxf(mx, s);
                }
            mx = fmaxf(mx, __shfl_xor(mx, 16));
            mx = fmaxf(mx, __shfl_xor(mx, 32));
            float sum = 0.f;
#pragma unroll
            for (int m = 0; m < 7; ++m)
#pragma unroll
                for (int r = 0; r < 4; ++r) {
                    float e = __expf(sacc[m][nt][r] - mx);
                    sacc[m][nt][r] = e;
                    sum += e;
                }
            sum += __shfl_xor(sum, 16);
            sum += __shfl_xor(sum, 32);
            float inv = 1.f / sum;
            const int rowNT = (nt == 0) ? row0 : row1;
#pragma unroll
            for (int m = 0; m < 7; ++m) {
                int dw = rowNT * 68 + m * 8 + g4 * 2;
                *(uint2*)&pbuf[dw] = make_uint2(pk2bf(sacc[m][nt][0] * inv, sacc[m][nt][1] * inv),
                                                pk2bf(sacc[m][nt][2] * inv, sacc[m][nt][3] * inv));
            }
        }
        // PV (wave-private pbuf rows; mt dbuf from global)
        __builtin_amdgcn_s_setprio(1);
#pragma unroll
        for (int kk = 0; kk < 4; ++kk) {
            if (kk < 3) {
#pragma unroll
                for (int m = 0; m < 4; ++m) mn[m] = *(const bf16x8*)(mt_p + (size_t)(m * 16) * 128 + (kk + 1) * 32);
            }
            bf16x8 pb0 = *(const bf16x8*)((const ushort*)pbuf + (size_t)row0 * 136 + kk * 32 + g4 * 8);
            bf16x8 pb1 = *(const bf16x8*)((const ushort*)pbuf + (size_t)row1 * 136 + kk * 32 + g4 * 8);
#pragma unroll
            for (int m = 0; m < 4; ++m) {
                pacc[m][0] = __builtin_amdgcn_mfma_f32_16x16x32_bf16(mc[m], pb0, pacc[m][0], 0, 0, 0);
                pacc[m][1] = __builtin_amdgcn_mfma_f32_16x16x32_bf16(mc[m], pb1, pacc[m][1], 0, 0, 0);
            }
            if (kk < 3) {
#pragma unroll
                for (int m = 0; m < 4; ++m) mc[m] = mn[m];
            }
        }
        __builtin_amdgcn_s_setprio(0);
    }
    const float* ginf = (st ? c_in : g_in) + (((size_t)b * 64) << 14);
    ushort* thb = (ushort*)(ws + OFF_XG) + ((size_t)b << 14) * 64;
#pragma unroll
    for (int nt = 0; nt < 2; ++nt) {
        const int ng = (nt == 0) ? ng0 : ng1;
        const int rowNT = (nt == 0) ? row0 : row1;
#pragma unroll
        for (int m = 0; m < 4; ++m) {
            float th[4], o4[4];
#pragma unroll
            for (int r = 0; r < 4; ++r) {
                int o = m * 16 + g4 * 4 + r;
                float v = pacc[m][nt][r];
                float xx = fminf(fmaxf(v, -15.f), 15.f);
                float e = __expf(2.f * xx);
                th[r] = __fdividef(e - 1.f, e + 1.f);
                o4[r] = th[r] + ginf[((size_t)o << 14) + ng];
            }
            int dw = rowNT * 68 + m * 8 + g4 * 2;
            *(uint2*)&pbuf[dw] = make_uint2(pk2bf(o4[0], o4[1]), pk2bf(o4[2], o4[3]));
            if (st == 0)
                *(uint2*)(thb + (size_t)ng * 64 + m * 16 + g4 * 4) =
                    make_uint2(pk2bf(th[0], th[1]), pk2bf(th[2], th[3]));
        }
    }
    const ushort* wtb = (const ushort*)(ws + OFF_WT);
    if (st == 0) {
        ushort* tfb = (ushort*)(ws + OFF_XF) + ((size_t)b << 20);
#pragma unroll
        for (int nt = 0; nt < 2; ++nt) {
            const int ng = (nt == 0) ? ng0 : ng1;
            const int rowNT = (nt == 0) ? row0 : row1;
            f32x4 at_[4];
#pragma unroll
            for (int m = 0; m < 4; ++m)
#pragma unroll
                for (int r = 0; r < 4; ++r) at_[m][r] = 0.f;
#pragma unroll
            for (int kk = 0; kk < 2; ++kk) {
                bf16x8 bx = *(const bf16x8*)((const ushort*)pbuf + (size_t)rowNT * 136 + kk * 32 + g4 * 8);
#pragma unroll
                for (int m = 0; m < 4; ++m) {
                    bf16x8 a_t = *(const bf16x8*)(wtb + (m * 16 + lr) * 64 + kk * 32 + g4 * 8);
                    at_[m] = __builtin_amdgcn_mfma_f32_16x16x32_bf16(a_t, bx, at_[m], 0, 0, 0);
                }
            }
#pragma unroll
            for (int m = 0; m < 4; ++m)
#pragma unroll
                for (int r = 0; r < 4; ++r) {
                    int o = m * 16 + g4 * 4 + r;
                    tfb[((size_t)o << 14) + ng] = f2bf(at_[m][r]);
                }
        }
    } else {
        float s[4][3];
#pragma unroll
        for (int m = 0; m < 4; ++m) { s[m][0] = 0.f; s[m][1] = 0.f; s[m][2] = 0.f; }
#pragma unroll
        for (int nt = 0; nt < 2; ++nt) {
            const int rowNT = (nt == 0) ? row0 : row1;
            f32x4 ap_[4], ag_[4];
#pragma unroll
            for (int m = 0; m < 4; ++m)
#pragma unroll
                for (int r = 0; r < 4; ++r) { ap_[m][r] = 0.f; ag_[m][r] = 0.f; }
#pragma unroll
            for (int kk = 0; kk < 2; ++kk) {
                bf16x8 bx = *(const bf16x8*)((const ushort*)pbuf + (size_t)rowNT * 136 + kk * 32 + g4 * 8);
#pragma unroll
                for (int m = 0; m < 4; ++m) {
                    const int ao = (m * 16 + lr) * 64 + kk * 32 + g4 * 8;
                    bf16x8 a_p = *(const bf16x8*)(wtb + 4096 + ao);
                    bf16x8 a_g = *(const bf16x8*)(wtb + 8192 + ao);
                    ap_[m] = __builtin_amdgcn_mfma_f32_16x16x32_bf16(a_p, bx, ap_[m], 0, 0, 0);
                    ag_[m] = __builtin_amdgcn_mfma_f32_16x16x32_bf16(a_g, bx, ag_[m], 0, 0, 0);
                }
            }
#pragma unroll
            for (int m = 0; m < 4; ++m)
#pragma unroll
                for (int r = 0; r < 4; ++r) {
                    float pv = ap_[m][r], gv = ag_[m][r];
                    s[m][0] += gv;
                    s[m][1] = fmaf(pv, gv, s[m][1]);
                    s[m][2] = fmaf(pv * pv, gv, s[m][2]);
                }
        }
#pragma unroll
        for (int off = 1; off < 32; off <<= 1)
#pragma unroll
            for (int m = 0; m < 4; ++m)
#pragma unroll
                for (int k = 0; k < 3; ++k) s[m][k] += __shfl_xor(s[m][k], off);
        if (l == 0 || l == 32) {
            const int h = g4 >> 1;
#pragma unroll
            for (int m = 0; m < 4; ++m)
#pragma unroll
                for (int k = 0; k < 3; ++k)
                    ws[OFF_PART + (size_t)((b * 8 + 2 * m + h) * 3 + k) * 512 + blockIdx.x * 4 + w] = s[m][k];
        }
    }
}

// ---------------- deterministic partial reduction -> attc raw sums ----------------
__global__ __launch_bounds__(64) void k_attc(float* __restrict__ ws) {
    const int id = blockIdx.x;
    const int l = threadIdx.x;
    const float4* v = (const float4*)(ws + OFF_PART + (size_t)id * 512 + l * 8);
    float4 a = v[0], b2 = v[1];
    float s = a.x + a.y + a.z + a.w + b2.x + b2.y + b2.z + b2.w;
#pragma unroll
    for (int off = 1; off < 64; off <<= 1) s += __shfl_xor(s, off);
    if (l == 0) ws[OFF_ATTC + id] = s;
}

// ---------------- GroupNorm stats v2 (t bf16) ----------------
__global__ __launch_bounds__(256) void k_stats2(float* __restrict__ ws, const float* __restrict__ zw) {
    __shared__ float r0[256], r1[256];
    const int nc = blockIdx.x, g = blockIdx.y, b = blockIdx.z, tid = threadIdx.x;
    const ushort* tfb = (const ushort*)(ws + OFF_XF) + ((size_t)(b * 64 + g * 8) << 14);
    const float* a = ws + OFF_ATTC + (size_t)(b * 8 + g) * 3;
    const float c0 = A0SQ * a[0], c1 = A1SQ * a[1], c2 = A2SQ * a[2];
    const float* z = zw + (size_t)g * 64;
    float sum = 0.f, ssq = 0.f;
    for (int n = nc * 2048 + tid; n < (nc + 1) * 2048; n += 256) {
        float y[8];
#pragma unroll
        for (int pl = 0; pl < 8; ++pl) { float tv = bf2f(tfb[((size_t)pl << 14) + n]); y[pl] = fmaf(fmaf(c2, tv, c1), tv, c0); }
#pragma unroll
        for (int o = 0; o < 8; ++o) {
            float xz = 0.f;
#pragma unroll
            for (int i2 = 0; i2 < 8; ++i2) xz = fmaf(z[o * 8 + i2], y[i2], xz);
            sum += xz; ssq = fmaf(xz, xz, ssq);
        }
    }
    r0[tid] = sum; r1[tid] = ssq;
    __syncthreads();
    for (int w = 128; w > 0; w >>= 1) {
        if (tid < w) { r0[tid] += r0[tid + w]; r1[tid] += r1[tid + w]; }
        __syncthreads();
    }
    if (tid == 0) {
        float* p2 = ws + OFF_PART2 + (size_t)((b * 8 + g) * 8 + nc) * 2;
        p2[0] = r0[0]; p2[1] = r1[0];
    }
}

// ---------------- combine stats partials -> mean/istd ----------------
__global__ __launch_bounds__(64) void k_mv(float* __restrict__ ws) {
    const int t = threadIdx.x;
    float sum = 0.f, ssq = 0.f;
    const float* p2 = ws + OFF_PART2 + (size_t)t * 16;
#pragma unroll
    for (int nc = 0; nc < 8; ++nc) { sum += p2[nc * 2]; ssq += p2[nc * 2 + 1]; }
    float mean = sum * (1.f / 131072.f);
    float var = ssq * (1.f / 131072.f) - mean * mean;
    float* mv = ws + OFF_MV + (size_t)t * 2;
    mv[0] = mean; mv[1] = rsqrtf(var + 1e-5f);
}

// ---------------- final: out = GN + tanh_bf16 + 2*input_g (t bf16) ----------------
__global__ __launch_bounds__(256) void k_final(float* __restrict__ ws, const float* __restrict__ zw,
                                               const float* __restrict__ gnw, const float* __restrict__ gnb,
                                               const float* __restrict__ g_in, float* __restrict__ out) {
    int id = blockIdx.x * 256 + threadIdx.x;
    int n = id & 16383; int g = (id >> 14) & 7; int b = id >> 17;
    const float* a = ws + OFF_ATTC + (size_t)(b * 8 + g) * 3;
    const float c0 = A0SQ * a[0], c1 = A1SQ * a[1], c2 = A2SQ * a[2];
    const float* mv = ws + OFF_MV + (size_t)(b * 8 + g) * 2;
    const float mean = mv[0], istd = mv[1];
    const float* z = zw + (size_t)g * 64;
    const ushort* tfb = (const ushort*)(ws + OFF_XF) + ((size_t)(b * 64 + g * 8) << 14) + n;
    float y[8];
#pragma unroll
    for (int pl = 0; pl < 8; ++pl) { float tv = bf2f(tfb[(size_t)pl << 14]); y[pl] = fmaf(fmaf(c2, tv, c1), tv, c0); }
    const ushort* thb = (const ushort*)(ws + OFF_XG) + (((size_t)b << 14) + n) * 64 + g * 8;
    ushort4 u0 = *(const ushort4*)thb;
    ushort4 u1 = *(const ushort4*)(thb + 4);
    float thv[8] = { bf2f(u0.x), bf2f(u0.y), bf2f(u0.z), bf2f(u0.w),
                     bf2f(u1.x), bf2f(u1.y), bf2f(u1.z), bf2f(u1.w) };
    const size_t cb = ((size_t)(b * 64 + g * 8) << 14) + n;
    const float* gi = g_in + cb;
    float* op = out + cb;
#pragma unroll
    for (int o = 0; o < 8; ++o) {
        float xz = 0.f;
#pragma unroll
        for (int i2 = 0; i2 < 8; ++i2) xz = fmaf(z[o * 8 + i2], y[i2], xz);
        int ch = g * 8 + o;
        float base = fmaf((xz - mean) * istd, gnw[ch], gnb[ch]) + thv[o];
        op[(size_t)o << 14] = fmaf(2.f, gi[(size_t)o << 14], base);
    }
}

// ---------------- host launch ----------------
extern "C" void kernel_launch(void* const* d_in, const int* in_sizes, int n_in,
                              void* d_out, int out_size, void* d_ws, size_t ws_size,
                              hipStream_t stream) {
    const float* in_g = (const float*)d_in[0];
    const float* in_c = (const float*)d_in[1];
    float* ws = (float*)d_ws;
    float* out = (float*)d_out;

    ushort* xqb  = (ushort*)(ws + OFF_XQ);
    ushort* xt_g = (ushort*)(ws + OFF_XT);
    ushort* xt_c = xt_g + 8388608;
    ushort* wt_g = (ushort*)(ws + OFF_XF);
    ushort* wt_c = wt_g + 73728;

    // input transpose + weight re-layout (bf16)
    k_xt<<<dim3(128, 8, 2), 256, 0, stream>>>(in_g, in_c, xt_g, xt_c);
    k_wt<<<576, 256, 0, stream>>>((const float*)d_in[20], (const float*)d_in[21], wt_g, wt_c);

    // MFMA convs v2 (proven best)
    k_convm2<<<dim3(128, 8, 2), 256, 0, stream>>>(xt_g, xt_c, wt_g, wt_c, xqb);

    // pyramid pooling v2 (plane-packed)
    PoolPtrs pp;
    pp.src[0] = (const float*)d_in[3];  pp.src[1] = (const float*)d_in[9];  pp.src[2] = (const float*)d_in[15];
    pp.src[3] = (const float*)d_in[2];  pp.src[4] = (const float*)d_in[8];  pp.src[5] = (const float*)d_in[14];
    k_pool2<<<2048, 256, 66560, stream>>>(pp, ws);

    // weight precomputes
    k_pkw<<<368, 256, 0, stream>>>((const float*)d_in[24], (const float*)d_in[25],
                                   (const float*)d_in[22], (const float*)d_in[23],
                                   (const float*)d_in[26], (const float*)d_in[27],
                                   (const float*)d_in[28], ws);

    // xk (bf16), xv (f32)
    KvPtrs kp;
    kp.k1[0] = (const float*)d_in[4];  kp.k1[1] = (const float*)d_in[10]; kp.k1[2] = (const float*)d_in[16];
    kp.k2[0] = (const float*)d_in[6];  kp.k2[1] = (const float*)d_in[12]; kp.k2[2] = (const float*)d_in[18];
    kp.v1[0] = (const float*)d_in[5];  kp.v1[1] = (const float*)d_in[11]; kp.v1[2] = (const float*)d_in[17];
    kp.v2[0] = (const float*)d_in[7];  kp.v2[1] = (const float*)d_in[13]; kp.v2[2] = (const float*)d_in[19];
    k_xkxv<<<5376, 256, 0, stream>>>(kp, ws);

    // MTb bf16
    k_mt<<<3072, 256, 0, stream>>>(ws);

    // fused MFMA attention v10 (aliased LDS union -> 4 blocks/CU)
    k_attn10<<<dim3(128, 8, 2), 256, 0, stream>>>(ws, in_g, in_c);

    // attc combine
    k_attc<<<192, 64, 0, stream>>>(ws);

    // GN stats (split) + combine, final
    k_stats2<<<dim3(8, 8, 8), 256, 0, stream>>>(ws, (const float*)d_in[29]);
    k_mv<<<1, 64, 0, stream>>>(ws);
    k_final<<<4096, 256, 0, stream>>>(ws, (const float*)d_in[29], (const float*)d_in[30],
                                      (const float*)d_in[31], in_g, out);
}

// Round 25
// 515.207 us; speedup vs baseline: 1.1358x; 1.1358x over previous
//
#include <hip/hip_runtime.h>
#include <math.h>

// ---------------- problem constants ----------------
constexpr int    BB      = 8;
constexpr int    NN      = 16384;
constexpr size_t SZ_XQ_ST = (size_t)BB * 128 * NN;
constexpr size_t SZ_XF_ST = (size_t)BB * 64 * NN;

// float-slot offsets in ws
constexpr size_t OFF_XQ   = 0;                          // xqb bf16 [2][8][16384][128]
constexpr size_t OFF_XT   = 16777216;                   // Xt bf16 [2][8][16384][64]
constexpr size_t OFF_XF   = 33554432;                   // t-field bf16 [8][64][16384] (attn st=0); Wt staging early
constexpr size_t OFF_XG   = OFF_XF + 8388608;           // tanh-only bf16 [8][16384][64] channel-last
constexpr size_t OFF_POOL = OFF_XF + 2 * SZ_XF_ST;      // pooled feats f32 (788,480)
constexpr size_t OFF_XK   = OFF_POOL + 788480;          // xkb bf16 [48][112][128]
constexpr size_t OFF_XV   = OFF_XK + 344064;            // xv f32 [48][128][112]
constexpr size_t OFF_MT   = OFF_XV + 688128;            // MTb bf16 [48][64][128]
constexpr size_t OFF_W    = OFF_MT + 393216;            // W f32 [2][3][64][192]
constexpr size_t OFF_AT   = OFF_W + 73728;              // ATb bf16 [2][64][64]
constexpr size_t OFF_WT   = OFF_AT + 4096;              // t/p/g w bf16 [3][64][64] row-major [o][c]
constexpr size_t OFF_ATTC = OFF_WT + 12288;             // [8][8][3] raw sums
constexpr size_t OFF_MV   = OFF_ATTC + 192;             // [8][8][2]
constexpr size_t OFF_PART = OFF_MV + 128;               // attc partials [192][512]
constexpr size_t OFF_PART2= OFF_PART + 98304;           // stats partials [64][8][2]

#define A0SQ 0.9998000199986667f
#define A1SQ 1.9996000399973335e-4f
#define A2SQ 1.9996000399973334e-8f

typedef __attribute__((ext_vector_type(8))) short bf16x8;
typedef __attribute__((ext_vector_type(4))) float f32x4;

__device__ inline ushort f2bf(float f) {
    uint u = __float_as_uint(f);
    return (ushort)((u + 0x7fffu + ((u >> 16) & 1u)) >> 16);
}
__device__ inline float bf2f(ushort u) { return __uint_as_float((uint)u << 16); }
// RNE pair pack (proven bits; do NOT use v_cvt_pk_bf16_f32 — RTZ, caused R9 fail)
__device__ inline uint pk2bf(float lo, float hi) {
    return (uint)f2bf(lo) | ((uint)f2bf(hi) << 16);
}

// ---------------- input transpose: f32 [64][128][128] -> bf16 [y][x][64] ----------------
__global__ __launch_bounds__(256) void k_xt(const float* __restrict__ in0, const float* __restrict__ in1,
                                            ushort* __restrict__ xt0, ushort* __restrict__ xt1) {
    __shared__ float L[64 * 130];
    const int y = blockIdx.x, b = blockIdx.y, tid = threadIdx.x;
    const float* in = blockIdx.z ? in1 : in0;
    ushort* xt = blockIdx.z ? xt1 : xt0;
    const float* ib = in + (((size_t)b * 64) << 14) + (y << 7);
    for (int r = 0; r < 32; ++r) {
        int idx = tid + (r << 8); int ch = idx >> 7; int x = idx & 127;
        L[ch * 130 + x] = ib[((size_t)ch << 14) + x];
    }
    __syncthreads();
    const int x = tid >> 1, seg = tid & 1;
    ushort* ob = xt + ((size_t)(b * 128 + y) * 128 + x) * 64 + seg * 32;
    uint pk[16];
#pragma unroll
    for (int c = 0; c < 16; ++c)
        pk[c] = pk2bf(L[(seg * 32 + 2 * c) * 130 + x], L[(seg * 32 + 2 * c + 1) * 130 + x]);
    uint4* o4 = (uint4*)ob;
#pragma unroll
    for (int c = 0; c < 4; ++c) o4[c] = make_uint4(pk[4 * c], pk[4 * c + 1], pk[4 * c + 2], pk[4 * c + 3]);
}

// ---------------- weight re-layout: f32 [oc][ic][3][3] -> bf16 [t][oc][ic] ----------------
__global__ __launch_bounds__(256) void k_wt(const float* __restrict__ w1, const float* __restrict__ w2,
                                            ushort* __restrict__ wt1, ushort* __restrict__ wt2) {
    int id = blockIdx.x * 256 + threadIdx.x;
    if (id >= 147456) return;
    int cs = id / 73728; int rem = id - cs * 73728;
    int t = rem >> 13; int oc = (rem >> 6) & 127; int ic = rem & 63;
    const float* w = cs ? w2 : w1;
    (cs ? wt2 : wt1)[rem] = f2bf(w[((size_t)(oc * 64 + ic)) * 9 + t]);
}

// ---------------- conv 3x3 SAME 64->128 bf16 MFMA v2 (proven best) ----------------
__global__ __launch_bounds__(256, 2) void k_convm2(const ushort* __restrict__ Xt0, const ushort* __restrict__ Xt1,
                                                   const ushort* __restrict__ Wt0, const ushort* __restrict__ Wt1,
                                                   ushort* __restrict__ out_base) {
    __shared__ ushort smem[3 * 130 * 72];
    const int tid = threadIdx.x;
    const int y = blockIdx.x, b = blockIdx.y;
    const ushort* Xt = blockIdx.z ? Xt1 : Xt0;
    const ushort* Wt = blockIdx.z ? Wt1 : Wt0;
    ushort* out = out_base + (size_t)blockIdx.z * 16777216;
    const int l = tid & 63;
    const int wv = __builtin_amdgcn_readfirstlane(tid >> 6);
    const int lr = l & 15;
    const int q = l >> 4;

    for (int slot = tid; slot < 390; slot += 256) {
        int dy = slot / 130, xx = slot - dy * 130;
        int row = y + dy - 1, sx = xx - 1;
        bool v = (row >= 0) & (row < 128) & (sx >= 0) & (sx < 128);
        const uint4* s = (const uint4*)(Xt + (((size_t)(b * 128 + row) * 128 + sx) * 64));
        uint4* d = (uint4*)(smem + (size_t)slot * 72);
        uint4 z = make_uint4(0, 0, 0, 0);
#pragma unroll
        for (int j = 0; j < 8; ++j) d[j] = v ? s[j] : z;
    }
    __syncthreads();

    f32x4 acc[2][8];
#pragma unroll
    for (int f = 0; f < 2; ++f)
#pragma unroll
        for (int g = 0; g < 8; ++g)
#pragma unroll
            for (int r = 0; r < 4; ++r) acc[f][g][r] = 0.f;

#pragma unroll
    for (int t = 0; t < 9; ++t) {
        const int dy = t / 3, dx = t - dy * 3;
#pragma unroll
        for (int h = 0; h < 2; ++h) {
            const int ko = h * 32 + q * 8;
            bf16x8 a0 = *(const bf16x8*)(Wt + ((size_t)(t * 128 + wv * 32 + lr) * 64 + ko));
            bf16x8 a1 = *(const bf16x8*)(Wt + ((size_t)(t * 128 + wv * 32 + 16 + lr) * 64 + ko));
#pragma unroll
            for (int g = 0; g < 8; ++g) {
                bf16x8 bb = *(const bf16x8*)(smem + (size_t)(dy * 130 + g * 16 + lr + dx) * 72 + ko);
                acc[0][g] = __builtin_amdgcn_mfma_f32_16x16x32_bf16(a0, bb, acc[0][g], 0, 0, 0);
                acc[1][g] = __builtin_amdgcn_mfma_f32_16x16x32_bf16(a1, bb, acc[1][g], 0, 0, 0);
            }
        }
    }
    __syncthreads();
    uint* T = (uint*)smem;
#pragma unroll
    for (int f = 0; f < 2; ++f)
#pragma unroll
        for (int g = 0; g < 8; ++g) {
            int dw = (g * 16 + lr) * 68 + wv * 16 + f * 8 + q * 2;
            T[dw] = pk2bf(acc[f][g][0], acc[f][g][1]);
            T[dw + 1] = pk2bf(acc[f][g][2], acc[f][g][3]);
        }
    __syncthreads();
    const int x = tid >> 1, sg = tid & 1;
    ushort* ob = out + ((size_t)(b * 128 + y) * 128 + x) * 128 + sg * 64;
    const uint* src = &T[x * 68 + sg * 32];
#pragma unroll
    for (int j = 0; j < 8; ++j) {
        uint4 vv = *(const uint4*)(src + 4 * j);
        *(uint4*)(ob + j * 8) = vv;
    }
}

// ---------------- pyramid pooling v2: plane-packed ----------------
struct PoolPtrs { const float* src[6]; };

__global__ __launch_bounds__(256) void k_pool2(PoolPtrs pp, float* __restrict__ ws) {
    extern __shared__ float P[];
    const int blk = blockIdx.x;
    const int tid = threadIdx.x;
    if (blk < 1024) {
        const int tI = (blk < 512) ? 0 : 3;
        const int local = (blk < 512) ? blk : blk - 512;
        const size_t toff = (tI == 0) ? 0 : 394240;
        const int h = 128, stride = 129;
        const float* img = pp.src[tI] + (size_t)local * h * h;
        for (int f = tid; f < h * h; f += 256) {
            int r = f >> 7; int cc = f & 127;
            P[r * stride + cc] = img[f];
        }
        __syncthreads();
        if (tid < h) {
            float cur = 0.f; const int rb = tid * stride;
            for (int cc = 0; cc < h; ++cc) { cur += P[rb + cc]; P[rb + cc] = cur; }
        }
        __syncthreads();
        if (tid < h) {
            float cur = 0.f;
            for (int r = 0; r < h; ++r) { int a = r * stride + tid; cur += P[a]; P[a] = cur; }
        }
        __syncthreads();
        if (tid < 110) {
            int s, off2;
            if (tid == 0)      { s = 1; off2 = 0; }
            else if (tid < 10) { s = 3; off2 = 1; }
            else if (tid < 46) { s = 6; off2 = 10; }
            else               { s = 8; off2 = 46; }
            int r = tid - off2; int j = r / s; int q = r - j * s;
            const int n = h + 2;
            int ra = (j * n) / s,       rb2 = ((j + 1) * n + s - 1) / s;
            int ca = (q * n) / s,       cb2 = ((q + 1) * n + s - 1) / s;
            float area = (float)((rb2 - ra) * (cb2 - ca));
            int r0 = ra - 1; if (r0 < 0) r0 = 0;  int r1 = rb2 - 1; if (r1 > h) r1 = h;
            int c0 = ca - 1; if (c0 < 0) c0 = 0;  int c1 = cb2 - 1; if (c1 > h) c1 = h;
            float ssum = 0.f;
            if (r1 > r0 && c1 > c0) {
                int ri = r1 - 1, rj = r0 - 1, ci = c1 - 1, cj = c0 - 1;
                float f11 = P[ri * stride + ci];
                float f01 = (rj < 0) ? 0.f : P[rj * stride + ci];
                float f10 = (cj < 0) ? 0.f : P[ri * stride + cj];
                float f00 = (rj < 0 || cj < 0) ? 0.f : P[rj * stride + cj];
                ssum = f11 - f01 - f10 + f00;
            }
            ws[OFF_POOL + toff + (size_t)local * 110 + tid] = ssum / area;
        }
    } else {
        int h, hs, tI, local0;
        if (blk < 1536) {
            h = 64; hs = 6;
            if (blk < 1280) { tI = 1; local0 = (blk - 1024) * 4; }
            else            { tI = 4; local0 = (blk - 1280) * 4; }
        } else {
            h = 32; hs = 5;
            if (blk < 1792) { tI = 2; local0 = (blk - 1536) * 8; }
            else            { tI = 5; local0 = (blk - 1792) * 8; }
        }
        const size_t toff = (tI == 1) ? 56320 : (tI == 4) ? 450560 : (tI == 2) ? 168960 : 563200;
        const int lg = tid >> hs;
        const int lr = tid & (h - 1);
        const int stride = h + 1;
        float* Pb = P + (size_t)lg * h * stride;
        const float* img = pp.src[tI] + (size_t)(local0 + lg) * h * h;
        for (int f = lr; f < h * h; f += h) {
            int r = f >> hs; int cc = f & (h - 1);
            Pb[r * stride + cc] = img[f];
        }
        __syncthreads();
        {
            float cur = 0.f; const int rb = lr * stride;
            for (int cc = 0; cc < h; ++cc) { cur += Pb[rb + cc]; Pb[rb + cc] = cur; }
        }
        __syncthreads();
        {
            float cur = 0.f;
            for (int r = 0; r < h; ++r) { int a = r * stride + lr; cur += Pb[a]; Pb[a] = cur; }
        }
        __syncthreads();
        for (int t = lr; t < 110; t += h) {
            int s, off2;
            if (t == 0)      { s = 1; off2 = 0; }
            else if (t < 10) { s = 3; off2 = 1; }
            else if (t < 46) { s = 6; off2 = 10; }
            else             { s = 8; off2 = 46; }
            int r = t - off2; int j = r / s; int q = r - j * s;
            const int n = h + 2;
            int ra = (j * n) / s,       rb2 = ((j + 1) * n + s - 1) / s;
            int ca = (q * n) / s,       cb2 = ((q + 1) * n + s - 1) / s;
            float area = (float)((rb2 - ra) * (cb2 - ca));
            int r0 = ra - 1; if (r0 < 0) r0 = 0;  int r1 = rb2 - 1; if (r1 > h) r1 = h;
            int c0 = ca - 1; if (c0 < 0) c0 = 0;  int c1 = cb2 - 1; if (c1 > h) c1 = h;
            float ssum = 0.f;
            if (r1 > r0 && c1 > c0) {
                int ri = r1 - 1, rj = r0 - 1, ci = c1 - 1, cj = c0 - 1;
                float f11 = Pb[ri * stride + ci];
                float f01 = (rj < 0) ? 0.f : Pb[rj * stride + ci];
                float f10 = (cj < 0) ? 0.f : Pb[ri * stride + cj];
                float f00 = (rj < 0 || cj < 0) ? 0.f : Pb[rj * stride + cj];
                ssum = f11 - f01 - f10 + f00;
            }
            ws[OFF_POOL + toff + (size_t)(local0 + lg) * 110 + t] = ssum / area;
        }
    }
}

// ---------------- small weight precomputes ----------------
__global__ __launch_bounds__(256) void k_pkw(const float* __restrict__ f1, const float* __restrict__ f2,
                                             const float* __restrict__ m1, const float* __restrict__ m2,
                                             const float* __restrict__ tw, const float* __restrict__ pw,
                                             const float* __restrict__ gw, float* __restrict__ ws) {
    int id = blockIdx.x * 256 + threadIdx.x;
    if (id < 73728) {
        int c = id % 192; int t = id / 192; int o = t & 63; int t2 = t >> 6; int i = t2 % 3; int st = t2 / 3;
        const float* fu = st ? f2 : f1; const float* ma = st ? m2 : m1;
        float s = 0.f;
        for (int k = 0; k < 64; ++k) s = fmaf(fu[o * 192 + i * 64 + k], ma[k * 192 + c], s);
        ws[OFF_W + id] = s;
    } else if (id < 81920) {
        int x = id - 73728; int o = x & 63; int c = (x >> 6) & 63; int st = x >> 12;
        const float* fu = st ? f2 : f1; const float* ma = st ? m2 : m1;
        float s = 0.f;
        for (int k = 0; k < 192; ++k) s = fmaf(fu[o * 192 + k], ma[(k & 63) * 192 + c], s);
        ((ushort*)(ws + OFF_AT))[(size_t)st * 4096 + o * 64 + c] = f2bf(s);
    } else if (id < 94208) {
        int x = id - 81920; int c = x & 63; int o = (x >> 6) & 63; int f = x >> 12;
        const float* src = (f == 0) ? tw : ((f == 1) ? pw : gw);
        ((ushort*)(ws + OFF_WT))[(size_t)f * 4096 + o * 64 + c] = f2bf(src[o * 64 + c]);
    }
}

// ---------------- xk (bf16 [p][c]) / xv (f32 [c][p]) from pooled features ----------------
struct KvPtrs { const float* k1[3]; const float* k2[3]; const float* v1[3]; const float* v2[3]; };

__global__ __launch_bounds__(256) void k_xkxv(KvPtrs kp, float* __restrict__ ws) {
    int id = blockIdx.x * 256 + threadIdx.x;
    int isV = 0;
    if (id >= 688128) { isV = 1; id -= 688128; }
    int p = id % 112; int t1 = id / 112; int C = t1 & 127; int t2 = t1 >> 7;
    int b = t2 & 7; int t3 = t2 >> 3; int i = t3 % 3; int st = t3 / 3;
    const int ci = 64 << i;
    size_t poff = (size_t)st * 394240 + (i >= 1 ? 56320 : 0) + (i >= 2 ? 112640 : 0);
    const float* kw = isV ? (st ? kp.v2[i] : kp.v1[i]) : (st ? kp.k2[i] : kp.k1[i]);
    float s = 0.f;
    if (p < 110) {
        const float* pl = ws + OFF_POOL + poff + (size_t)b * ci * 110 + p;
        for (int ic = 0; ic < ci; ++ic) s = fmaf(kw[C * ci + ic], pl[(size_t)ic * 110], s);
    }
    if (isV) ws[OFF_XV + id] = s;
    else     ((ushort*)(ws + OFF_XK))[(size_t)t2 * 14336 + p * 128 + C] = f2bf(s);
}

// ---------------- MTb bf16 [t2][o][p(128, zero-pad)] ----------------
__global__ __launch_bounds__(256) void k_mt(float* __restrict__ ws) {
    int id = blockIdx.x * 256 + threadIdx.x;
    int p = id & 127; int o = (id >> 7) & 63; int t2 = id >> 13;
    int sti = t2 >> 3;
    float s = 0.f;
    if (p < 110) {
        const float* Wrow = ws + OFF_W + ((size_t)sti * 64 + o) * 192 + 64;
        const float* xv = ws + OFF_XV + (size_t)t2 * 128 * 112 + p;
        for (int r = 0; r < 128; ++r) s = fmaf(Wrow[r], xv[(size_t)r * 112], s);
    }
    ((ushort*)(ws + OFF_MT))[id] = f2bf(s);
}

// ---------------- fused MFMA attention v10b: union LDS, 3 blocks/CU (no spill) ----------------
__global__ __launch_bounds__(256, 3) void k_attn10(float* __restrict__ ws,
                                                   const float* __restrict__ g_in,
                                                   const float* __restrict__ c_in) {
    __shared__ uint ubuf[128 * 68];                     // 34,816 B union: xk stage (S phase) / P+xf tile (PV phase)
    uint* pbuf = ubuf;
    ushort* xks = (ushort*)ubuf;                        // same 68-dword row pitch for both views
    const int tid = threadIdx.x;
    const int w = __builtin_amdgcn_readfirstlane(tid >> 6);
    const int l = tid & 63;
    const int lr = l & 15;
    const int g4 = l >> 4;
    const int n0 = blockIdx.x << 7;
    const int b = blockIdx.y;
    const int st = blockIdx.z;

    const ushort* xqb = (const ushort*)(ws + OFF_XQ);
    const ushort* xkb = (const ushort*)(ws + OFF_XK);
    const ushort* mtb = (const ushort*)(ws + OFF_MT);
    const ushort* atb = (const ushort*)(ws + OFF_AT) + (size_t)st * 4096;
    const ushort* xt  = (const ushort*)(ws + OFF_XT) + (size_t)st * 8388608 + ((size_t)b << 14) * 64;

    const int ng0 = n0 + (2 * w + 0) * 16 + lr;
    const int ng1 = n0 + (2 * w + 1) * 16 + lr;
    const int row0 = w * 32 + lr;
    const int row1 = w * 32 + 16 + lr;
    const int padrow = w * 32 + (l >> 1);
    const int padcol = 56 + ((l & 1) << 2);

    bf16x8 bq[2][4];
    {
        const ushort* p0 = xqb + ((size_t)(st * 8 + b) * 16384 + ng0) * 128 + g4 * 8;
        const ushort* p1 = xqb + ((size_t)(st * 8 + b) * 16384 + ng1) * 128 + g4 * 8;
#pragma unroll
        for (int kk = 0; kk < 4; ++kk) { bq[0][kk] = *(const bf16x8*)(p0 + kk * 32); bq[1][kk] = *(const bf16x8*)(p1 + kk * 32); }
    }

    f32x4 pacc[4][2];
#pragma unroll
    for (int m = 0; m < 4; ++m)
#pragma unroll
        for (int nt = 0; nt < 2; ++nt)
#pragma unroll
            for (int r = 0; r < 4; ++r) pacc[m][nt][r] = 0.f;

    // residual-matrix term A(64x64) @ in
#pragma unroll
    for (int kk = 0; kk < 2; ++kk) {
        bf16x8 bi0 = *(const bf16x8*)(xt + (size_t)ng0 * 64 + kk * 32 + g4 * 8);
        bf16x8 bi1 = *(const bf16x8*)(xt + (size_t)ng1 * 64 + kk * 32 + g4 * 8);
#pragma unroll
        for (int m = 0; m < 4; ++m) {
            bf16x8 a = *(const bf16x8*)(atb + (m * 16 + lr) * 64 + kk * 32 + g4 * 8);
            pacc[m][0] = __builtin_amdgcn_mfma_f32_16x16x32_bf16(a, bi0, pacc[m][0], 0, 0, 0);
            pacc[m][1] = __builtin_amdgcn_mfma_f32_16x16x32_bf16(a, bi1, pacc[m][1], 0, 0, 0);
        }
    }

#pragma unroll 1
    for (int i = 0; i < 3; ++i) {
        // cooperative stage of xk[i] into union LDS (prior PV must be done)
        if (i > 0) __syncthreads();
        {
            const ushort* src = xkb + (size_t)((st * 3 + i) * 8 + b) * 14336;
#pragma unroll
            for (int s2 = 0; s2 < 7; ++s2) {
                int idx = (s2 * 256 + tid) * 8;         // ushort index, 1792 uint4 total
                int row = idx >> 7; int col = idx & 127;
                *(uint4*)(xks + row * 136 + col) = *(const uint4*)(src + idx);
            }
        }
        __syncthreads();

        const ushort* mt_p = mtb + (size_t)((st * 3 + i) * 8 + b) * 8192 + (size_t)lr * 128 + g4 * 8;
        f32x4 sacc[7][2];
#pragma unroll
        for (int m = 0; m < 7; ++m)
#pragma unroll
            for (int nt = 0; nt < 2; ++nt)
#pragma unroll
                for (int r = 0; r < 4; ++r) sacc[m][nt][r] = 0.f;
        // S = xk^T @ xq from LDS
        __builtin_amdgcn_s_setprio(1);
#pragma unroll
        for (int kk = 0; kk < 4; ++kk) {
#pragma unroll
            for (int m = 0; m < 7; ++m) {
                bf16x8 a = *(const bf16x8*)(xks + (m * 16 + lr) * 136 + kk * 32 + g4 * 8);
                sacc[m][0] = __builtin_amdgcn_mfma_f32_16x16x32_bf16(a, bq[0][kk], sacc[m][0], 0, 0, 0);
                sacc[m][1] = __builtin_amdgcn_mfma_f32_16x16x32_bf16(a, bq[1][kk], sacc[m][1], 0, 0, 0);
            }
        }
        __builtin_amdgcn_s_setprio(0);
        // prefetch PV kk=0 A-fragments before the barrier (global, latency overlaps barrier wait)
        bf16x8 mc[4], mn[4];
#pragma unroll
        for (int m = 0; m < 4; ++m) mc[m] = *(const bf16x8*)(mt_p + (size_t)(m * 16) * 128);
        // all waves done reading xks before P overwrites the union
        __syncthreads();
        // re-zero p=112..127 pad in this wave's rows (staging clobbered it)
        *(uint4*)&pbuf[padrow * 68 + padcol] = make_uint4(0, 0, 0, 0);
        // in-register softmax over p for both nt, mask p>=110, clip +-64
#pragma unroll
        for (int nt = 0; nt < 2; ++nt) {
            float mx = -3.0e38f;
#pragma unroll
            for (int m = 0; m < 7; ++m)
#pragma unroll
                for (int r = 0; r < 4; ++r) {
                    int p = m * 16 + g4 * 4 + r;
                    float s = fminf(fmaxf(sacc[m][nt][r], -64.f), 64.f);
                    if (p >= 110) s = -3.0e38f;
                    sacc[m][nt][r] = s;
                    mx = fmaxf(mx, s);
                }
            mx = fmaxf(mx, __shfl_xor(mx, 16));
            mx = fmaxf(mx, __shfl_xor(mx, 32));
            float sum = 0.f;
#pragma unroll
            for (int m = 0; m < 7; ++m)
#pragma unroll
                for (int r = 0; r < 4; ++r) {
                    float e = __expf(sacc[m][nt][r] - mx);
                    sacc[m][nt][r] = e;
                    sum += e;
                }
            sum += __shfl_xor(sum, 16);
            sum += __shfl_xor(sum, 32);
            float inv = 1.f / sum;
            const int rowNT = (nt == 0) ? row0 : row1;
#pragma unroll
            for (int m = 0; m < 7; ++m) {
                int dw = rowNT * 68 + m * 8 + g4 * 2;
                *(uint2*)&pbuf[dw] = make_uint2(pk2bf(sacc[m][nt][0] * inv, sacc[m][nt][1] * inv),
                                                pk2bf(sacc[m][nt][2] * inv, sacc[m][nt][3] * inv));
            }
        }
        // PV (wave-private pbuf rows; mt dbuf from global)
        __builtin_amdgcn_s_setprio(1);
#pragma unroll
        for (int kk = 0; kk < 4; ++kk) {
            if (kk < 3) {
#pragma unroll
                for (int m = 0; m < 4; ++m) mn[m] = *(const bf16x8*)(mt_p + (size_t)(m * 16) * 128 + (kk + 1) * 32);
            }
            bf16x8 pb0 = *(const bf16x8*)((const ushort*)pbuf + (size_t)row0 * 136 + kk * 32 + g4 * 8);
            bf16x8 pb1 = *(const bf16x8*)((const ushort*)pbuf + (size_t)row1 * 136 + kk * 32 + g4 * 8);
#pragma unroll
            for (int m = 0; m < 4; ++m) {
                pacc[m][0] = __builtin_amdgcn_mfma_f32_16x16x32_bf16(mc[m], pb0, pacc[m][0], 0, 0, 0);
                pacc[m][1] = __builtin_amdgcn_mfma_f32_16x16x32_bf16(mc[m], pb1, pacc[m][1], 0, 0, 0);
            }
            if (kk < 3) {
#pragma unroll
                for (int m = 0; m < 4; ++m) mc[m] = mn[m];
            }
        }
        __builtin_amdgcn_s_setprio(0);
    }
    const float* ginf = (st ? c_in : g_in) + (((size_t)b * 64) << 14);
    ushort* thb = (ushort*)(ws + OFF_XG) + ((size_t)b << 14) * 64;
#pragma unroll
    for (int nt = 0; nt < 2; ++nt) {
        const int ng = (nt == 0) ? ng0 : ng1;
        const int rowNT = (nt == 0) ? row0 : row1;
#pragma unroll
        for (int m = 0; m < 4; ++m) {
            float th[4], o4[4];
#pragma unroll
            for (int r = 0; r < 4; ++r) {
                int o = m * 16 + g4 * 4 + r;
                float v = pacc[m][nt][r];
                float xx = fminf(fmaxf(v, -15.f), 15.f);
                float e = __expf(2.f * xx);
                th[r] = __fdividef(e - 1.f, e + 1.f);
                o4[r] = th[r] + ginf[((size_t)o << 14) + ng];
            }
            int dw = rowNT * 68 + m * 8 + g4 * 2;
            *(uint2*)&pbuf[dw] = make_uint2(pk2bf(o4[0], o4[1]), pk2bf(o4[2], o4[3]));
            if (st == 0)
                *(uint2*)(thb + (size_t)ng * 64 + m * 16 + g4 * 4) =
                    make_uint2(pk2bf(th[0], th[1]), pk2bf(th[2], th[3]));
        }
    }
    const ushort* wtb = (const ushort*)(ws + OFF_WT);
    if (st == 0) {
        ushort* tfb = (ushort*)(ws + OFF_XF) + ((size_t)b << 20);
#pragma unroll
        for (int nt = 0; nt < 2; ++nt) {
            const int ng = (nt == 0) ? ng0 : ng1;
            const int rowNT = (nt == 0) ? row0 : row1;
            f32x4 at_[4];
#pragma unroll
            for (int m = 0; m < 4; ++m)
#pragma unroll
                for (int r = 0; r < 4; ++r) at_[m][r] = 0.f;
#pragma unroll
            for (int kk = 0; kk < 2; ++kk) {
                bf16x8 bx = *(const bf16x8*)((const ushort*)pbuf + (size_t)rowNT * 136 + kk * 32 + g4 * 8);
#pragma unroll
                for (int m = 0; m < 4; ++m) {
                    bf16x8 a_t = *(const bf16x8*)(wtb + (m * 16 + lr) * 64 + kk * 32 + g4 * 8);
                    at_[m] = __builtin_amdgcn_mfma_f32_16x16x32_bf16(a_t, bx, at_[m], 0, 0, 0);
                }
            }
#pragma unroll
            for (int m = 0; m < 4; ++m)
#pragma unroll
                for (int r = 0; r < 4; ++r) {
                    int o = m * 16 + g4 * 4 + r;
                    tfb[((size_t)o << 14) + ng] = f2bf(at_[m][r]);
                }
        }
    } else {
        float s[4][3];
#pragma unroll
        for (int m = 0; m < 4; ++m) { s[m][0] = 0.f; s[m][1] = 0.f; s[m][2] = 0.f; }
#pragma unroll
        for (int nt = 0; nt < 2; ++nt) {
            const int rowNT = (nt == 0) ? row0 : row1;
            f32x4 ap_[4], ag_[4];
#pragma unroll
            for (int m = 0; m < 4; ++m)
#pragma unroll
                for (int r = 0; r < 4; ++r) { ap_[m][r] = 0.f; ag_[m][r] = 0.f; }
#pragma unroll
            for (int kk = 0; kk < 2; ++kk) {
                bf16x8 bx = *(const bf16x8*)((const ushort*)pbuf + (size_t)rowNT * 136 + kk * 32 + g4 * 8);
#pragma unroll
                for (int m = 0; m < 4; ++m) {
                    const int ao = (m * 16 + lr) * 64 + kk * 32 + g4 * 8;
                    bf16x8 a_p = *(const bf16x8*)(wtb + 4096 + ao);
                    bf16x8 a_g = *(const bf16x8*)(wtb + 8192 + ao);
                    ap_[m] = __builtin_amdgcn_mfma_f32_16x16x32_bf16(a_p, bx, ap_[m], 0, 0, 0);
                    ag_[m] = __builtin_amdgcn_mfma_f32_16x16x32_bf16(a_g, bx, ag_[m], 0, 0, 0);
                }
            }
#pragma unroll
            for (int m = 0; m < 4; ++m)
#pragma unroll
                for (int r = 0; r < 4; ++r) {
                    float pv = ap_[m][r], gv = ag_[m][r];
                    s[m][0] += gv;
                    s[m][1] = fmaf(pv, gv, s[m][1]);
                    s[m][2] = fmaf(pv * pv, gv, s[m][2]);
                }
        }
#pragma unroll
        for (int off = 1; off < 32; off <<= 1)
#pragma unroll
            for (int m = 0; m < 4; ++m)
#pragma unroll
                for (int k = 0; k < 3; ++k) s[m][k] += __shfl_xor(s[m][k], off);
        if (l == 0 || l == 32) {
            const int h = g4 >> 1;
#pragma unroll
            for (int m = 0; m < 4; ++m)
#pragma unroll
                for (int k = 0; k < 3; ++k)
                    ws[OFF_PART + (size_t)((b * 8 + 2 * m + h) * 3 + k) * 512 + blockIdx.x * 4 + w] = s[m][k];
        }
    }
}

// ---------------- deterministic partial reduction -> attc raw sums ----------------
__global__ __launch_bounds__(64) void k_attc(float* __restrict__ ws) {
    const int id = blockIdx.x;
    const int l = threadIdx.x;
    const float4* v = (const float4*)(ws + OFF_PART + (size_t)id * 512 + l * 8);
    float4 a = v[0], b2 = v[1];
    float s = a.x + a.y + a.z + a.w + b2.x + b2.y + b2.z + b2.w;
#pragma unroll
    for (int off = 1; off < 64; off <<= 1) s += __shfl_xor(s, off);
    if (l == 0) ws[OFF_ATTC + id] = s;
}

// ---------------- GroupNorm stats v2 (t bf16) ----------------
__global__ __launch_bounds__(256) void k_stats2(float* __restrict__ ws, const float* __restrict__ zw) {
    __shared__ float r0[256], r1[256];
    const int nc = blockIdx.x, g = blockIdx.y, b = blockIdx.z, tid = threadIdx.x;
    const ushort* tfb = (const ushort*)(ws + OFF_XF) + ((size_t)(b * 64 + g * 8) << 14);
    const float* a = ws + OFF_ATTC + (size_t)(b * 8 + g) * 3;
    const float c0 = A0SQ * a[0], c1 = A1SQ * a[1], c2 = A2SQ * a[2];
    const float* z = zw + (size_t)g * 64;
    float sum = 0.f, ssq = 0.f;
    for (int n = nc * 2048 + tid; n < (nc + 1) * 2048; n += 256) {
        float y[8];
#pragma unroll
        for (int pl = 0; pl < 8; ++pl) { float tv = bf2f(tfb[((size_t)pl << 14) + n]); y[pl] = fmaf(fmaf(c2, tv, c1), tv, c0); }
#pragma unroll
        for (int o = 0; o < 8; ++o) {
            float xz = 0.f;
#pragma unroll
            for (int i2 = 0; i2 < 8; ++i2) xz = fmaf(z[o * 8 + i2], y[i2], xz);
            sum += xz; ssq = fmaf(xz, xz, ssq);
        }
    }
    r0[tid] = sum; r1[tid] = ssq;
    __syncthreads();
    for (int w = 128; w > 0; w >>= 1) {
        if (tid < w) { r0[tid] += r0[tid + w]; r1[tid] += r1[tid + w]; }
        __syncthreads();
    }
    if (tid == 0) {
        float* p2 = ws + OFF_PART2 + (size_t)((b * 8 + g) * 8 + nc) * 2;
        p2[0] = r0[0]; p2[1] = r1[0];
    }
}

// ---------------- combine stats partials -> mean/istd ----------------
__global__ __launch_bounds__(64) void k_mv(float* __restrict__ ws) {
    const int t = threadIdx.x;
    float sum = 0.f, ssq = 0.f;
    const float* p2 = ws + OFF_PART2 + (size_t)t * 16;
#pragma unroll
    for (int nc = 0; nc < 8; ++nc) { sum += p2[nc * 2]; ssq += p2[nc * 2 + 1]; }
    float mean = sum * (1.f / 131072.f);
    float var = ssq * (1.f / 131072.f) - mean * mean;
    float* mv = ws + OFF_MV + (size_t)t * 2;
    mv[0] = mean; mv[1] = rsqrtf(var + 1e-5f);
}

// ---------------- final: out = GN + tanh_bf16 + 2*input_g (t bf16) ----------------
__global__ __launch_bounds__(256) void k_final(float* __restrict__ ws, const float* __restrict__ zw,
                                               const float* __restrict__ gnw, const float* __restrict__ gnb,
                                               const float* __restrict__ g_in, float* __restrict__ out) {
    int id = blockIdx.x * 256 + threadIdx.x;
    int n = id & 16383; int g = (id >> 14) & 7; int b = id >> 17;
    const float* a = ws + OFF_ATTC + (size_t)(b * 8 + g) * 3;
    const float c0 = A0SQ * a[0], c1 = A1SQ * a[1], c2 = A2SQ * a[2];
    const float* mv = ws + OFF_MV + (size_t)(b * 8 + g) * 2;
    const float mean = mv[0], istd = mv[1];
    const float* z = zw + (size_t)g * 64;
    const ushort* tfb = (const ushort*)(ws + OFF_XF) + ((size_t)(b * 64 + g * 8) << 14) + n;
    float y[8];
#pragma unroll
    for (int pl = 0; pl < 8; ++pl) { float tv = bf2f(tfb[(size_t)pl << 14]); y[pl] = fmaf(fmaf(c2, tv, c1), tv, c0); }
    const ushort* thb = (const ushort*)(ws + OFF_XG) + (((size_t)b << 14) + n) * 64 + g * 8;
    ushort4 u0 = *(const ushort4*)thb;
    ushort4 u1 = *(const ushort4*)(thb + 4);
    float thv[8] = { bf2f(u0.x), bf2f(u0.y), bf2f(u0.z), bf2f(u0.w),
                     bf2f(u1.x), bf2f(u1.y), bf2f(u1.z), bf2f(u1.w) };
    const size_t cb = ((size_t)(b * 64 + g * 8) << 14) + n;
    const float* gi = g_in + cb;
    float* op = out + cb;
#pragma unroll
    for (int o = 0; o < 8; ++o) {
        float xz = 0.f;
#pragma unroll
        for (int i2 = 0; i2 < 8; ++i2) xz = fmaf(z[o * 8 + i2], y[i2], xz);
        int ch = g * 8 + o;
        float base = fmaf((xz - mean) * istd, gnw[ch], gnb[ch]) + thv[o];
        op[(size_t)o << 14] = fmaf(2.f, gi[(size_t)o << 14], base);
    }
}

// ---------------- host launch ----------------
extern "C" void kernel_launch(void* const* d_in, const int* in_sizes, int n_in,
                              void* d_out, int out_size, void* d_ws, size_t ws_size,
                              hipStream_t stream) {
    const float* in_g = (const float*)d_in[0];
    const float* in_c = (const float*)d_in[1];
    float* ws = (float*)d_ws;
    float* out = (float*)d_out;

    ushort* xqb  = (ushort*)(ws + OFF_XQ);
    ushort* xt_g = (ushort*)(ws + OFF_XT);
    ushort* xt_c = xt_g + 8388608;
    ushort* wt_g = (ushort*)(ws + OFF_XF);
    ushort* wt_c = wt_g + 73728;

    // input transpose + weight re-layout (bf16)
    k_xt<<<dim3(128, 8, 2), 256, 0, stream>>>(in_g, in_c, xt_g, xt_c);
    k_wt<<<576, 256, 0, stream>>>((const float*)d_in[20], (const float*)d_in[21], wt_g, wt_c);

    // MFMA convs v2 (proven best)
    k_convm2<<<dim3(128, 8, 2), 256, 0, stream>>>(xt_g, xt_c, wt_g, wt_c, xqb);

    // pyramid pooling v2 (plane-packed)
    PoolPtrs pp;
    pp.src[0] = (const float*)d_in[3];  pp.src[1] = (const float*)d_in[9];  pp.src[2] = (const float*)d_in[15];
    pp.src[3] = (const float*)d_in[2];  pp.src[4] = (const float*)d_in[8];  pp.src[5] = (const float*)d_in[14];
    k_pool2<<<2048, 256, 66560, stream>>>(pp, ws);

    // weight precomputes
    k_pkw<<<368, 256, 0, stream>>>((const float*)d_in[24], (const float*)d_in[25],
                                   (const float*)d_in[22], (const float*)d_in[23],
                                   (const float*)d_in[26], (const float*)d_in[27],
                                   (const float*)d_in[28], ws);

    // xk (bf16), xv (f32)
    KvPtrs kp;
    kp.k1[0] = (const float*)d_in[4];  kp.k1[1] = (const float*)d_in[10]; kp.k1[2] = (const float*)d_in[16];
    kp.k2[0] = (const float*)d_in[6];  kp.k2[1] = (const float*)d_in[12]; kp.k2[2] = (const float*)d_in[18];
    kp.v1[0] = (const float*)d_in[5];  kp.v1[1] = (const float*)d_in[11]; kp.v1[2] = (const float*)d_in[17];
    kp.v2[0] = (const float*)d_in[7];  kp.v2[1] = (const float*)d_in[13]; kp.v2[2] = (const float*)d_in[19];
    k_xkxv<<<5376, 256, 0, stream>>>(kp, ws);

    // MTb bf16
    k_mt<<<3072, 256, 0, stream>>>(ws);

    // fused MFMA attention v10b (union LDS, 3 blocks/CU)
    k_attn10<<<dim3(128, 8, 2), 256, 0, stream>>>(ws, in_g, in_c);

    // attc combine
    k_attc<<<192, 64, 0, stream>>>(ws);

    // GN stats (split) + combine, final
    k_stats2<<<dim3(8, 8, 8), 256, 0, stream>>>(ws, (const float*)d_in[29]);
    k_mv<<<1, 64, 0, stream>>>(ws);
    k_final<<<4096, 256, 0, stream>>>(ws, (const float*)d_in[29], (const float*)d_in[30],
                                      (const float*)d_in[31], in_g, out);
}

// Round 26
// 491.958 us; speedup vs baseline: 1.1895x; 1.0473x over previous
//
#include <hip/hip_runtime.h>
#include <math.h>

// ---------------- problem constants ----------------
constexpr int    BB      = 8;
constexpr int    NN      = 16384;
constexpr size_t SZ_XQ_ST = (size_t)BB * 128 * NN;
constexpr size_t SZ_XF_ST = (size_t)BB * 64 * NN;

// float-slot offsets in ws
constexpr size_t OFF_XQ   = 0;                          // xqb bf16 [2][8][16384][128]
constexpr size_t OFF_XT   = 16777216;                   // Xt bf16 [2][8][16384][64]
constexpr size_t OFF_XF   = 33554432;                   // t-field bf16 [8][64][16384] (attn st=0); Wt staging early
constexpr size_t OFF_XG   = OFF_XF + 8388608;           // tanh-only bf16 [8][16384][64] channel-last
constexpr size_t OFF_POOL = OFF_XF + 2 * SZ_XF_ST;      // pooled feats f32 (788,480)
constexpr size_t OFF_XK   = OFF_POOL + 788480;          // xkb bf16 [48][112][128]
constexpr size_t OFF_XV   = OFF_XK + 344064;            // xv f32 [48][128][112]
constexpr size_t OFF_MT   = OFF_XV + 688128;            // MTb bf16 [48][64][128]
constexpr size_t OFF_W    = OFF_MT + 393216;            // W f32 [2][3][64][192]
constexpr size_t OFF_AT   = OFF_W + 73728;              // ATb bf16 [2][64][64]
constexpr size_t OFF_WT   = OFF_AT + 4096;              // t/p/g w bf16 [3][64][64] row-major [o][c]
constexpr size_t OFF_ATTC = OFF_WT + 12288;             // [8][8][3] raw sums
constexpr size_t OFF_MV   = OFF_ATTC + 192;             // [8][8][2]
constexpr size_t OFF_PART = OFF_MV + 128;               // attc partials [192][512]
constexpr size_t OFF_PART2= OFF_PART + 98304;           // stats partials [64][8][2]

#define A0SQ 0.9998000199986667f
#define A1SQ 1.9996000399973335e-4f
#define A2SQ 1.9996000399973334e-8f

typedef __attribute__((ext_vector_type(8))) short bf16x8;
typedef __attribute__((ext_vector_type(4))) float f32x4;

__device__ inline ushort f2bf(float f) {
    uint u = __float_as_uint(f);
    return (ushort)((u + 0x7fffu + ((u >> 16) & 1u)) >> 16);
}
__device__ inline float bf2f(ushort u) { return __uint_as_float((uint)u << 16); }
// RNE pair pack (proven bits; do NOT use v_cvt_pk_bf16_f32 — RTZ, caused R9 fail)
__device__ inline uint pk2bf(float lo, float hi) {
    return (uint)f2bf(lo) | ((uint)f2bf(hi) << 16);
}

// ---------------- input transpose: f32 [64][128][128] -> bf16 [y][x][64] ----------------
__global__ __launch_bounds__(256) void k_xt(const float* __restrict__ in0, const float* __restrict__ in1,
                                            ushort* __restrict__ xt0, ushort* __restrict__ xt1) {
    __shared__ float L[64 * 130];
    const int y = blockIdx.x, b = blockIdx.y, tid = threadIdx.x;
    const float* in = blockIdx.z ? in1 : in0;
    ushort* xt = blockIdx.z ? xt1 : xt0;
    const float* ib = in + (((size_t)b * 64) << 14) + (y << 7);
    for (int r = 0; r < 32; ++r) {
        int idx = tid + (r << 8); int ch = idx >> 7; int x = idx & 127;
        L[ch * 130 + x] = ib[((size_t)ch << 14) + x];
    }
    __syncthreads();
    const int x = tid >> 1, seg = tid & 1;
    ushort* ob = xt + ((size_t)(b * 128 + y) * 128 + x) * 64 + seg * 32;
    uint pk[16];
#pragma unroll
    for (int c = 0; c < 16; ++c)
        pk[c] = pk2bf(L[(seg * 32 + 2 * c) * 130 + x], L[(seg * 32 + 2 * c + 1) * 130 + x]);
    uint4* o4 = (uint4*)ob;
#pragma unroll
    for (int c = 0; c < 4; ++c) o4[c] = make_uint4(pk[4 * c], pk[4 * c + 1], pk[4 * c + 2], pk[4 * c + 3]);
}

// ---------------- weight re-layout: f32 [oc][ic][3][3] -> bf16 [t][oc][ic] ----------------
__global__ __launch_bounds__(256) void k_wt(const float* __restrict__ w1, const float* __restrict__ w2,
                                            ushort* __restrict__ wt1, ushort* __restrict__ wt2) {
    int id = blockIdx.x * 256 + threadIdx.x;
    if (id >= 147456) return;
    int cs = id / 73728; int rem = id - cs * 73728;
    int t = rem >> 13; int oc = (rem >> 6) & 127; int ic = rem & 63;
    const float* w = cs ? w2 : w1;
    (cs ? wt2 : wt1)[rem] = f2bf(w[((size_t)(oc * 64 + ic)) * 9 + t]);
}

// ---------------- conv 3x3 SAME 64->128 bf16 MFMA v2 (proven best) ----------------
__global__ __launch_bounds__(256, 2) void k_convm2(const ushort* __restrict__ Xt0, const ushort* __restrict__ Xt1,
                                                   const ushort* __restrict__ Wt0, const ushort* __restrict__ Wt1,
                                                   ushort* __restrict__ out_base) {
    __shared__ ushort smem[3 * 130 * 72];
    const int tid = threadIdx.x;
    const int y = blockIdx.x, b = blockIdx.y;
    const ushort* Xt = blockIdx.z ? Xt1 : Xt0;
    const ushort* Wt = blockIdx.z ? Wt1 : Wt0;
    ushort* out = out_base + (size_t)blockIdx.z * 16777216;
    const int l = tid & 63;
    const int wv = __builtin_amdgcn_readfirstlane(tid >> 6);
    const int lr = l & 15;
    const int q = l >> 4;

    for (int slot = tid; slot < 390; slot += 256) {
        int dy = slot / 130, xx = slot - dy * 130;
        int row = y + dy - 1, sx = xx - 1;
        bool v = (row >= 0) & (row < 128) & (sx >= 0) & (sx < 128);
        const uint4* s = (const uint4*)(Xt + (((size_t)(b * 128 + row) * 128 + sx) * 64));
        uint4* d = (uint4*)(smem + (size_t)slot * 72);
        uint4 z = make_uint4(0, 0, 0, 0);
#pragma unroll
        for (int j = 0; j < 8; ++j) d[j] = v ? s[j] : z;
    }
    __syncthreads();

    f32x4 acc[2][8];
#pragma unroll
    for (int f = 0; f < 2; ++f)
#pragma unroll
        for (int g = 0; g < 8; ++g)
#pragma unroll
            for (int r = 0; r < 4; ++r) acc[f][g][r] = 0.f;

#pragma unroll
    for (int t = 0; t < 9; ++t) {
        const int dy = t / 3, dx = t - dy * 3;
#pragma unroll
        for (int h = 0; h < 2; ++h) {
            const int ko = h * 32 + q * 8;
            bf16x8 a0 = *(const bf16x8*)(Wt + ((size_t)(t * 128 + wv * 32 + lr) * 64 + ko));
            bf16x8 a1 = *(const bf16x8*)(Wt + ((size_t)(t * 128 + wv * 32 + 16 + lr) * 64 + ko));
#pragma unroll
            for (int g = 0; g < 8; ++g) {
                bf16x8 bb = *(const bf16x8*)(smem + (size_t)(dy * 130 + g * 16 + lr + dx) * 72 + ko);
                acc[0][g] = __builtin_amdgcn_mfma_f32_16x16x32_bf16(a0, bb, acc[0][g], 0, 0, 0);
                acc[1][g] = __builtin_amdgcn_mfma_f32_16x16x32_bf16(a1, bb, acc[1][g], 0, 0, 0);
            }
        }
    }
    __syncthreads();
    uint* T = (uint*)smem;
#pragma unroll
    for (int f = 0; f < 2; ++f)
#pragma unroll
        for (int g = 0; g < 8; ++g) {
            int dw = (g * 16 + lr) * 68 + wv * 16 + f * 8 + q * 2;
            T[dw] = pk2bf(acc[f][g][0], acc[f][g][1]);
            T[dw + 1] = pk2bf(acc[f][g][2], acc[f][g][3]);
        }
    __syncthreads();
    const int x = tid >> 1, sg = tid & 1;
    ushort* ob = out + ((size_t)(b * 128 + y) * 128 + x) * 128 + sg * 64;
    const uint* src = &T[x * 68 + sg * 32];
#pragma unroll
    for (int j = 0; j < 8; ++j) {
        uint4 vv = *(const uint4*)(src + 4 * j);
        *(uint4*)(ob + j * 8) = vv;
    }
}

// ---------------- pyramid pooling v2: plane-packed ----------------
struct PoolPtrs { const float* src[6]; };

__global__ __launch_bounds__(256) void k_pool2(PoolPtrs pp, float* __restrict__ ws) {
    extern __shared__ float P[];
    const int blk = blockIdx.x;
    const int tid = threadIdx.x;
    if (blk < 1024) {
        const int tI = (blk < 512) ? 0 : 3;
        const int local = (blk < 512) ? blk : blk - 512;
        const size_t toff = (tI == 0) ? 0 : 394240;
        const int h = 128, stride = 129;
        const float* img = pp.src[tI] + (size_t)local * h * h;
        for (int f = tid; f < h * h; f += 256) {
            int r = f >> 7; int cc = f & 127;
            P[r * stride + cc] = img[f];
        }
        __syncthreads();
        if (tid < h) {
            float cur = 0.f; const int rb = tid * stride;
            for (int cc = 0; cc < h; ++cc) { cur += P[rb + cc]; P[rb + cc] = cur; }
        }
        __syncthreads();
        if (tid < h) {
            float cur = 0.f;
            for (int r = 0; r < h; ++r) { int a = r * stride + tid; cur += P[a]; P[a] = cur; }
        }
        __syncthreads();
        if (tid < 110) {
            int s, off2;
            if (tid == 0)      { s = 1; off2 = 0; }
            else if (tid < 10) { s = 3; off2 = 1; }
            else if (tid < 46) { s = 6; off2 = 10; }
            else               { s = 8; off2 = 46; }
            int r = tid - off2; int j = r / s; int q = r - j * s;
            const int n = h + 2;
            int ra = (j * n) / s,       rb2 = ((j + 1) * n + s - 1) / s;
            int ca = (q * n) / s,       cb2 = ((q + 1) * n + s - 1) / s;
            float area = (float)((rb2 - ra) * (cb2 - ca));
            int r0 = ra - 1; if (r0 < 0) r0 = 0;  int r1 = rb2 - 1; if (r1 > h) r1 = h;
            int c0 = ca - 1; if (c0 < 0) c0 = 0;  int c1 = cb2 - 1; if (c1 > h) c1 = h;
            float ssum = 0.f;
            if (r1 > r0 && c1 > c0) {
                int ri = r1 - 1, rj = r0 - 1, ci = c1 - 1, cj = c0 - 1;
                float f11 = P[ri * stride + ci];
                float f01 = (rj < 0) ? 0.f : P[rj * stride + ci];
                float f10 = (cj < 0) ? 0.f : P[ri * stride + cj];
                float f00 = (rj < 0 || cj < 0) ? 0.f : P[rj * stride + cj];
                ssum = f11 - f01 - f10 + f00;
            }
            ws[OFF_POOL + toff + (size_t)local * 110 + tid] = ssum / area;
        }
    } else {
        int h, hs, tI, local0;
        if (blk < 1536) {
            h = 64; hs = 6;
            if (blk < 1280) { tI = 1; local0 = (blk - 1024) * 4; }
            else            { tI = 4; local0 = (blk - 1280) * 4; }
        } else {
            h = 32; hs = 5;
            if (blk < 1792) { tI = 2; local0 = (blk - 1536) * 8; }
            else            { tI = 5; local0 = (blk - 1792) * 8; }
        }
        const size_t toff = (tI == 1) ? 56320 : (tI == 4) ? 450560 : (tI == 2) ? 168960 : 563200;
        const int lg = tid >> hs;
        const int lr = tid & (h - 1);
        const int stride = h + 1;
        float* Pb = P + (size_t)lg * h * stride;
        const float* img = pp.src[tI] + (size_t)(local0 + lg) * h * h;
        for (int f = lr; f < h * h; f += h) {
            int r = f >> hs; int cc = f & (h - 1);
            Pb[r * stride + cc] = img[f];
        }
        __syncthreads();
        {
            float cur = 0.f; const int rb = lr * stride;
            for (int cc = 0; cc < h; ++cc) { cur += Pb[rb + cc]; Pb[rb + cc] = cur; }
        }
        __syncthreads();
        {
            float cur = 0.f;
            for (int r = 0; r < h; ++r) { int a = r * stride + lr; cur += Pb[a]; Pb[a] = cur; }
        }
        __syncthreads();
        for (int t = lr; t < 110; t += h) {
            int s, off2;
            if (t == 0)      { s = 1; off2 = 0; }
            else if (t < 10) { s = 3; off2 = 1; }
            else if (t < 46) { s = 6; off2 = 10; }
            else             { s = 8; off2 = 46; }
            int r = t - off2; int j = r / s; int q = r - j * s;
            const int n = h + 2;
            int ra = (j * n) / s,       rb2 = ((j + 1) * n + s - 1) / s;
            int ca = (q * n) / s,       cb2 = ((q + 1) * n + s - 1) / s;
            float area = (float)((rb2 - ra) * (cb2 - ca));
            int r0 = ra - 1; if (r0 < 0) r0 = 0;  int r1 = rb2 - 1; if (r1 > h) r1 = h;
            int c0 = ca - 1; if (c0 < 0) c0 = 0;  int c1 = cb2 - 1; if (c1 > h) c1 = h;
            float ssum = 0.f;
            if (r1 > r0 && c1 > c0) {
                int ri = r1 - 1, rj = r0 - 1, ci = c1 - 1, cj = c0 - 1;
                float f11 = Pb[ri * stride + ci];
                float f01 = (rj < 0) ? 0.f : Pb[rj * stride + ci];
                float f10 = (cj < 0) ? 0.f : Pb[ri * stride + cj];
                float f00 = (rj < 0 || cj < 0) ? 0.f : Pb[rj * stride + cj];
                ssum = f11 - f01 - f10 + f00;
            }
            ws[OFF_POOL + toff + (size_t)(local0 + lg) * 110 + t] = ssum / area;
        }
    }
}

// ---------------- small weight precomputes ----------------
__global__ __launch_bounds__(256) void k_pkw(const float* __restrict__ f1, const float* __restrict__ f2,
                                             const float* __restrict__ m1, const float* __restrict__ m2,
                                             const float* __restrict__ tw, const float* __restrict__ pw,
                                             const float* __restrict__ gw, float* __restrict__ ws) {
    int id = blockIdx.x * 256 + threadIdx.x;
    if (id < 73728) {
        int c = id % 192; int t = id / 192; int o = t & 63; int t2 = t >> 6; int i = t2 % 3; int st = t2 / 3;
        const float* fu = st ? f2 : f1; const float* ma = st ? m2 : m1;
        float s = 0.f;
        for (int k = 0; k < 64; ++k) s = fmaf(fu[o * 192 + i * 64 + k], ma[k * 192 + c], s);
        ws[OFF_W + id] = s;
    } else if (id < 81920) {
        int x = id - 73728; int o = x & 63; int c = (x >> 6) & 63; int st = x >> 12;
        const float* fu = st ? f2 : f1; const float* ma = st ? m2 : m1;
        float s = 0.f;
        for (int k = 0; k < 192; ++k) s = fmaf(fu[o * 192 + k], ma[(k & 63) * 192 + c], s);
        ((ushort*)(ws + OFF_AT))[(size_t)st * 4096 + o * 64 + c] = f2bf(s);
    } else if (id < 94208) {
        int x = id - 81920; int c = x & 63; int o = (x >> 6) & 63; int f = x >> 12;
        const float* src = (f == 0) ? tw : ((f == 1) ? pw : gw);
        ((ushort*)(ws + OFF_WT))[(size_t)f * 4096 + o * 64 + c] = f2bf(src[o * 64 + c]);
    }
}

// ---------------- xk (bf16 [p][c]) / xv (f32 [c][p]) from pooled features ----------------
struct KvPtrs { const float* k1[3]; const float* k2[3]; const float* v1[3]; const float* v2[3]; };

__global__ __launch_bounds__(256) void k_xkxv(KvPtrs kp, float* __restrict__ ws) {
    int id = blockIdx.x * 256 + threadIdx.x;
    int isV = 0;
    if (id >= 688128) { isV = 1; id -= 688128; }
    int p = id % 112; int t1 = id / 112; int C = t1 & 127; int t2 = t1 >> 7;
    int b = t2 & 7; int t3 = t2 >> 3; int i = t3 % 3; int st = t3 / 3;
    const int ci = 64 << i;
    size_t poff = (size_t)st * 394240 + (i >= 1 ? 56320 : 0) + (i >= 2 ? 112640 : 0);
    const float* kw = isV ? (st ? kp.v2[i] : kp.v1[i]) : (st ? kp.k2[i] : kp.k1[i]);
    float s = 0.f;
    if (p < 110) {
        const float* pl = ws + OFF_POOL + poff + (size_t)b * ci * 110 + p;
        for (int ic = 0; ic < ci; ++ic) s = fmaf(kw[C * ci + ic], pl[(size_t)ic * 110], s);
    }
    if (isV) ws[OFF_XV + id] = s;
    else     ((ushort*)(ws + OFF_XK))[(size_t)t2 * 14336 + p * 128 + C] = f2bf(s);
}

// ---------------- MTb bf16 [t2][o][p(128, zero-pad)] ----------------
__global__ __launch_bounds__(256) void k_mt(float* __restrict__ ws) {
    int id = blockIdx.x * 256 + threadIdx.x;
    int p = id & 127; int o = (id >> 7) & 63; int t2 = id >> 13;
    int sti = t2 >> 3;
    float s = 0.f;
    if (p < 110) {
        const float* Wrow = ws + OFF_W + ((size_t)sti * 64 + o) * 192 + 64;
        const float* xv = ws + OFF_XV + (size_t)t2 * 128 * 112 + p;
        for (int r = 0; r < 128; ++r) s = fmaf(Wrow[r], xv[(size_t)r * 112], s);
    }
    ((ushort*)(ws + OFF_MT))[id] = f2bf(s);
}

// ---------------- fused MFMA attention v8: cooperative xk LDS staging ----------------
__global__ __launch_bounds__(256, 2) void k_attn8(float* __restrict__ ws,
                                                  const float* __restrict__ g_in,
                                                  const float* __restrict__ c_in) {
    __shared__ uint pbuf[128 * 68];                     // 34,816 B (P bf16 + xf tile), wave-private rows
    __shared__ ushort xks[112 * 136];                   // 30,464 B staged xk, pitch 136 (16B-aligned rows)
    const int tid = threadIdx.x;
    const int w = __builtin_amdgcn_readfirstlane(tid >> 6);
    const int l = tid & 63;
    const int lr = l & 15;
    const int g4 = l >> 4;
    const int n0 = blockIdx.x << 7;
    const int b = blockIdx.y;
    const int st = blockIdx.z;

    const ushort* xqb = (const ushort*)(ws + OFF_XQ);
    const ushort* xkb = (const ushort*)(ws + OFF_XK);
    const ushort* mtb = (const ushort*)(ws + OFF_MT);
    const ushort* atb = (const ushort*)(ws + OFF_AT) + (size_t)st * 4096;
    const ushort* xt  = (const ushort*)(ws + OFF_XT) + (size_t)st * 8388608 + ((size_t)b << 14) * 64;

    // zero p=112..127 pad in this wave's 32 rows (wave-private)
    {
        int row = w * 32 + (l >> 1);
        int dcol = 56 + ((l & 1) << 2);
#pragma unroll
        for (int j = 0; j < 4; ++j) pbuf[row * 68 + dcol + j] = 0;
    }
    const int ng0 = n0 + (2 * w + 0) * 16 + lr;
    const int ng1 = n0 + (2 * w + 1) * 16 + lr;
    const int row0 = w * 32 + lr;
    const int row1 = w * 32 + 16 + lr;

    bf16x8 bq[2][4];
    {
        const ushort* p0 = xqb + ((size_t)(st * 8 + b) * 16384 + ng0) * 128 + g4 * 8;
        const ushort* p1 = xqb + ((size_t)(st * 8 + b) * 16384 + ng1) * 128 + g4 * 8;
#pragma unroll
        for (int kk = 0; kk < 4; ++kk) { bq[0][kk] = *(const bf16x8*)(p0 + kk * 32); bq[1][kk] = *(const bf16x8*)(p1 + kk * 32); }
    }

    f32x4 pacc[4][2];
#pragma unroll
    for (int m = 0; m < 4; ++m)
#pragma unroll
        for (int nt = 0; nt < 2; ++nt)
#pragma unroll
            for (int r = 0; r < 4; ++r) pacc[m][nt][r] = 0.f;

    // residual-matrix term A(64x64) @ in
#pragma unroll
    for (int kk = 0; kk < 2; ++kk) {
        bf16x8 bi0 = *(const bf16x8*)(xt + (size_t)ng0 * 64 + kk * 32 + g4 * 8);
        bf16x8 bi1 = *(const bf16x8*)(xt + (size_t)ng1 * 64 + kk * 32 + g4 * 8);
#pragma unroll
        for (int m = 0; m < 4; ++m) {
            bf16x8 a = *(const bf16x8*)(atb + (m * 16 + lr) * 64 + kk * 32 + g4 * 8);
            pacc[m][0] = __builtin_amdgcn_mfma_f32_16x16x32_bf16(a, bi0, pacc[m][0], 0, 0, 0);
            pacc[m][1] = __builtin_amdgcn_mfma_f32_16x16x32_bf16(a, bi1, pacc[m][1], 0, 0, 0);
        }
    }

#pragma unroll 1
    for (int i = 0; i < 3; ++i) {
        // cooperative stage of xk[i] into LDS (pitch 136, coalesced uint4)
        if (i > 0) __syncthreads();                     // prior S-loop done across all waves
        {
            const ushort* src = xkb + (size_t)((st * 3 + i) * 8 + b) * 14336;
#pragma unroll
            for (int s2 = 0; s2 < 7; ++s2) {
                int idx = (s2 * 256 + tid) * 8;         // ushort index, 1792 uint4 total
                int row = idx >> 7; int col = idx & 127;
                *(uint4*)(xks + row * 136 + col) = *(const uint4*)(src + idx);
            }
        }
        __syncthreads();

        const ushort* mt_p = mtb + (size_t)((st * 3 + i) * 8 + b) * 8192 + (size_t)lr * 128 + g4 * 8;
        f32x4 sacc[7][2];
#pragma unroll
        for (int m = 0; m < 7; ++m)
#pragma unroll
            for (int nt = 0; nt < 2; ++nt)
#pragma unroll
                for (int r = 0; r < 4; ++r) sacc[m][nt][r] = 0.f;
        // S = xk^T @ xq from LDS
        __builtin_amdgcn_s_setprio(1);
#pragma unroll
        for (int kk = 0; kk < 4; ++kk) {
#pragma unroll
            for (int m = 0; m < 7; ++m) {
                bf16x8 a = *(const bf16x8*)(xks + (m * 16 + lr) * 136 + kk * 32 + g4 * 8);
                sacc[m][0] = __builtin_amdgcn_mfma_f32_16x16x32_bf16(a, bq[0][kk], sacc[m][0], 0, 0, 0);
                sacc[m][1] = __builtin_amdgcn_mfma_f32_16x16x32_bf16(a, bq[1][kk], sacc[m][1], 0, 0, 0);
            }
        }
        __builtin_amdgcn_s_setprio(0);
        // prefetch PV kk=0 A-fragments before softmax (global, dbuf as before)
        bf16x8 mc[4], mn[4];
#pragma unroll
        for (int m = 0; m < 4; ++m) mc[m] = *(const bf16x8*)(mt_p + (size_t)(m * 16) * 128);
        // in-register softmax over p for both nt, mask p>=110, clip +-64
#pragma unroll
        for (int nt = 0; nt < 2; ++nt) {
            float mx = -3.0e38f;
#pragma unroll
            for (int m = 0; m < 7; ++m)
#pragma unroll
                for (int r = 0; r < 4; ++r) {
                    int p = m * 16 + g4 * 4 + r;
                    float s = fminf(fmaxf(sacc[m][nt][r], -64.f), 64.f);
                    if (p >= 110) s = -3.0e38f;
                    sacc[m][nt][r] = s;
                    mx = fmaxf(mx, s);
                }
            mx = fmaxf(mx, __shfl_xor(mx, 16));
            mx = fmaxf(mx, __shfl_xor(mx, 32));
            float sum = 0.f;
#pragma unroll
            for (int m = 0; m < 7; ++m)
#pragma unroll
                for (int r = 0; r < 4; ++r) {
                    float e = __expf(sacc[m][nt][r] - mx);
                    sacc[m][nt][r] = e;
                    sum += e;
                }
            sum += __shfl_xor(sum, 16);
            sum += __shfl_xor(sum, 32);
            float inv = 1.f / sum;
            const int rowNT = (nt == 0) ? row0 : row1;
#pragma unroll
            for (int m = 0; m < 7; ++m) {
                int dw = rowNT * 68 + m * 8 + g4 * 2;
                pbuf[dw] = pk2bf(sacc[m][nt][0] * inv, sacc[m][nt][1] * inv);
                pbuf[dw + 1] = pk2bf(sacc[m][nt][2] * inv, sacc[m][nt][3] * inv);
            }
        }
        // PV (wave-private pbuf; mt dbuf from global)
        __builtin_amdgcn_s_setprio(1);
#pragma unroll
        for (int kk = 0; kk < 4; ++kk) {
            if (kk < 3) {
#pragma unroll
                for (int m = 0; m < 4; ++m) mn[m] = *(const bf16x8*)(mt_p + (size_t)(m * 16) * 128 + (kk + 1) * 32);
            }
            bf16x8 pb0 = *(const bf16x8*)((const ushort*)pbuf + (size_t)row0 * 136 + kk * 32 + g4 * 8);
            bf16x8 pb1 = *(const bf16x8*)((const ushort*)pbuf + (size_t)row1 * 136 + kk * 32 + g4 * 8);
#pragma unroll
            for (int m = 0; m < 4; ++m) {
                pacc[m][0] = __builtin_amdgcn_mfma_f32_16x16x32_bf16(mc[m], pb0, pacc[m][0], 0, 0, 0);
                pacc[m][1] = __builtin_amdgcn_mfma_f32_16x16x32_bf16(mc[m], pb1, pacc[m][1], 0, 0, 0);
            }
            if (kk < 3) {
#pragma unroll
                for (int m = 0; m < 4; ++m) mc[m] = mn[m];
            }
        }
        __builtin_amdgcn_s_setprio(0);
    }
    const float* ginf = (st ? c_in : g_in) + (((size_t)b * 64) << 14);
    ushort* thb = (ushort*)(ws + OFF_XG) + ((size_t)b << 14) * 64;
#pragma unroll
    for (int nt = 0; nt < 2; ++nt) {
        const int ng = (nt == 0) ? ng0 : ng1;
        const int rowNT = (nt == 0) ? row0 : row1;
#pragma unroll
        for (int m = 0; m < 4; ++m) {
            float th[4], o4[4];
#pragma unroll
            for (int r = 0; r < 4; ++r) {
                int o = m * 16 + g4 * 4 + r;
                float v = pacc[m][nt][r];
                float xx = fminf(fmaxf(v, -15.f), 15.f);
                float e = __expf(2.f * xx);
                th[r] = __fdividef(e - 1.f, e + 1.f);
                o4[r] = th[r] + ginf[((size_t)o << 14) + ng];
            }
            int dw = rowNT * 68 + m * 8 + g4 * 2;
            pbuf[dw] = pk2bf(o4[0], o4[1]);
            pbuf[dw + 1] = pk2bf(o4[2], o4[3]);
            if (st == 0)
                *(uint2*)(thb + (size_t)ng * 64 + m * 16 + g4 * 4) =
                    make_uint2(pk2bf(th[0], th[1]), pk2bf(th[2], th[3]));
        }
    }
    const ushort* wtb = (const ushort*)(ws + OFF_WT);
    if (st == 0) {
        ushort* tfb = (ushort*)(ws + OFF_XF) + ((size_t)b << 20);
#pragma unroll
        for (int nt = 0; nt < 2; ++nt) {
            const int ng = (nt == 0) ? ng0 : ng1;
            const int rowNT = (nt == 0) ? row0 : row1;
            f32x4 at_[4];
#pragma unroll
            for (int m = 0; m < 4; ++m)
#pragma unroll
                for (int r = 0; r < 4; ++r) at_[m][r] = 0.f;
#pragma unroll
            for (int kk = 0; kk < 2; ++kk) {
                bf16x8 bx = *(const bf16x8*)((const ushort*)pbuf + (size_t)rowNT * 136 + kk * 32 + g4 * 8);
#pragma unroll
                for (int m = 0; m < 4; ++m) {
                    bf16x8 a_t = *(const bf16x8*)(wtb + (m * 16 + lr) * 64 + kk * 32 + g4 * 8);
                    at_[m] = __builtin_amdgcn_mfma_f32_16x16x32_bf16(a_t, bx, at_[m], 0, 0, 0);
                }
            }
#pragma unroll
            for (int m = 0; m < 4; ++m)
#pragma unroll
                for (int r = 0; r < 4; ++r) {
                    int o = m * 16 + g4 * 4 + r;
                    tfb[((size_t)o << 14) + ng] = f2bf(at_[m][r]);
                }
        }
    } else {
        float s[4][3];
#pragma unroll
        for (int m = 0; m < 4; ++m) { s[m][0] = 0.f; s[m][1] = 0.f; s[m][2] = 0.f; }
#pragma unroll
        for (int nt = 0; nt < 2; ++nt) {
            const int rowNT = (nt == 0) ? row0 : row1;
            f32x4 ap_[4], ag_[4];
#pragma unroll
            for (int m = 0; m < 4; ++m)
#pragma unroll
                for (int r = 0; r < 4; ++r) { ap_[m][r] = 0.f; ag_[m][r] = 0.f; }
#pragma unroll
            for (int kk = 0; kk < 2; ++kk) {
                bf16x8 bx = *(const bf16x8*)((const ushort*)pbuf + (size_t)rowNT * 136 + kk * 32 + g4 * 8);
#pragma unroll
                for (int m = 0; m < 4; ++m) {
                    const int ao = (m * 16 + lr) * 64 + kk * 32 + g4 * 8;
                    bf16x8 a_p = *(const bf16x8*)(wtb + 4096 + ao);
                    bf16x8 a_g = *(const bf16x8*)(wtb + 8192 + ao);
                    ap_[m] = __builtin_amdgcn_mfma_f32_16x16x32_bf16(a_p, bx, ap_[m], 0, 0, 0);
                    ag_[m] = __builtin_amdgcn_mfma_f32_16x16x32_bf16(a_g, bx, ag_[m], 0, 0, 0);
                }
            }
#pragma unroll
            for (int m = 0; m < 4; ++m)
#pragma unroll
                for (int r = 0; r < 4; ++r) {
                    float pv = ap_[m][r], gv = ag_[m][r];
                    s[m][0] += gv;
                    s[m][1] = fmaf(pv, gv, s[m][1]);
                    s[m][2] = fmaf(pv * pv, gv, s[m][2]);
                }
        }
#pragma unroll
        for (int off = 1; off < 32; off <<= 1)
#pragma unroll
            for (int m = 0; m < 4; ++m)
#pragma unroll
                for (int k = 0; k < 3; ++k) s[m][k] += __shfl_xor(s[m][k], off);
        if (l == 0 || l == 32) {
            const int h = g4 >> 1;
#pragma unroll
            for (int m = 0; m < 4; ++m)
#pragma unroll
                for (int k = 0; k < 3; ++k)
                    ws[OFF_PART + (size_t)((b * 8 + 2 * m + h) * 3 + k) * 512 + blockIdx.x * 4 + w] = s[m][k];
        }
    }
}

// ---------------- deterministic partial reduction -> attc raw sums ----------------
__global__ __launch_bounds__(64) void k_attc(float* __restrict__ ws) {
    const int id = blockIdx.x;
    const int l = threadIdx.x;
    const float4* v = (const float4*)(ws + OFF_PART + (size_t)id * 512 + l * 8);
    float4 a = v[0], b2 = v[1];
    float s = a.x + a.y + a.z + a.w + b2.x + b2.y + b2.z + b2.w;
#pragma unroll
    for (int off = 1; off < 64; off <<= 1) s += __shfl_xor(s, off);
    if (l == 0) ws[OFF_ATTC + id] = s;
}

// ---------------- GroupNorm stats v2 (t bf16) ----------------
__global__ __launch_bounds__(256) void k_stats2(float* __restrict__ ws, const float* __restrict__ zw) {
    __shared__ float r0[256], r1[256];
    const int nc = blockIdx.x, g = blockIdx.y, b = blockIdx.z, tid = threadIdx.x;
    const ushort* tfb = (const ushort*)(ws + OFF_XF) + ((size_t)(b * 64 + g * 8) << 14);
    const float* a = ws + OFF_ATTC + (size_t)(b * 8 + g) * 3;
    const float c0 = A0SQ * a[0], c1 = A1SQ * a[1], c2 = A2SQ * a[2];
    const float* z = zw + (size_t)g * 64;
    float sum = 0.f, ssq = 0.f;
    for (int n = nc * 2048 + tid; n < (nc + 1) * 2048; n += 256) {
        float y[8];
#pragma unroll
        for (int pl = 0; pl < 8; ++pl) { float tv = bf2f(tfb[((size_t)pl << 14) + n]); y[pl] = fmaf(fmaf(c2, tv, c1), tv, c0); }
#pragma unroll
        for (int o = 0; o < 8; ++o) {
            float xz = 0.f;
#pragma unroll
            for (int i2 = 0; i2 < 8; ++i2) xz = fmaf(z[o * 8 + i2], y[i2], xz);
            sum += xz; ssq = fmaf(xz, xz, ssq);
        }
    }
    r0[tid] = sum; r1[tid] = ssq;
    __syncthreads();
    for (int w = 128; w > 0; w >>= 1) {
        if (tid < w) { r0[tid] += r0[tid + w]; r1[tid] += r1[tid + w]; }
        __syncthreads();
    }
    if (tid == 0) {
        float* p2 = ws + OFF_PART2 + (size_t)((b * 8 + g) * 8 + nc) * 2;
        p2[0] = r0[0]; p2[1] = r1[0];
    }
}

// ---------------- combine stats partials -> mean/istd ----------------
__global__ __launch_bounds__(64) void k_mv(float* __restrict__ ws) {
    const int t = threadIdx.x;
    float sum = 0.f, ssq = 0.f;
    const float* p2 = ws + OFF_PART2 + (size_t)t * 16;
#pragma unroll
    for (int nc = 0; nc < 8; ++nc) { sum += p2[nc * 2]; ssq += p2[nc * 2 + 1]; }
    float mean = sum * (1.f / 131072.f);
    float var = ssq * (1.f / 131072.f) - mean * mean;
    float* mv = ws + OFF_MV + (size_t)t * 2;
    mv[0] = mean; mv[1] = rsqrtf(var + 1e-5f);
}

// ---------------- final: out = GN + tanh_bf16 + 2*input_g (t bf16) ----------------
__global__ __launch_bounds__(256) void k_final(float* __restrict__ ws, const float* __restrict__ zw,
                                               const float* __restrict__ gnw, const float* __restrict__ gnb,
                                               const float* __restrict__ g_in, float* __restrict__ out) {
    int id = blockIdx.x * 256 + threadIdx.x;
    int n = id & 16383; int g = (id >> 14) & 7; int b = id >> 17;
    const float* a = ws + OFF_ATTC + (size_t)(b * 8 + g) * 3;
    const float c0 = A0SQ * a[0], c1 = A1SQ * a[1], c2 = A2SQ * a[2];
    const float* mv = ws + OFF_MV + (size_t)(b * 8 + g) * 2;
    const float mean = mv[0], istd = mv[1];
    const float* z = zw + (size_t)g * 64;
    const ushort* tfb = (const ushort*)(ws + OFF_XF) + ((size_t)(b * 64 + g * 8) << 14) + n;
    float y[8];
#pragma unroll
    for (int pl = 0; pl < 8; ++pl) { float tv = bf2f(tfb[(size_t)pl << 14]); y[pl] = fmaf(fmaf(c2, tv, c1), tv, c0); }
    const ushort* thb = (const ushort*)(ws + OFF_XG) + (((size_t)b << 14) + n) * 64 + g * 8;
    ushort4 u0 = *(const ushort4*)thb;
    ushort4 u1 = *(const ushort4*)(thb + 4);
    float thv[8] = { bf2f(u0.x), bf2f(u0.y), bf2f(u0.z), bf2f(u0.w),
                     bf2f(u1.x), bf2f(u1.y), bf2f(u1.z), bf2f(u1.w) };
    const size_t cb = ((size_t)(b * 64 + g * 8) << 14) + n;
    const float* gi = g_in + cb;
    float* op = out + cb;
#pragma unroll
    for (int o = 0; o < 8; ++o) {
        float xz = 0.f;
#pragma unroll
        for (int i2 = 0; i2 < 8; ++i2) xz = fmaf(z[o * 8 + i2], y[i2], xz);
        int ch = g * 8 + o;
        float base = fmaf((xz - mean) * istd, gnw[ch], gnb[ch]) + thv[o];
        op[(size_t)o << 14] = fmaf(2.f, gi[(size_t)o << 14], base);
    }
}

// ---------------- host launch ----------------
extern "C" void kernel_launch(void* const* d_in, const int* in_sizes, int n_in,
                              void* d_out, int out_size, void* d_ws, size_t ws_size,
                              hipStream_t stream) {
    const float* in_g = (const float*)d_in[0];
    const float* in_c = (const float*)d_in[1];
    float* ws = (float*)d_ws;
    float* out = (float*)d_out;

    ushort* xqb  = (ushort*)(ws + OFF_XQ);
    ushort* xt_g = (ushort*)(ws + OFF_XT);
    ushort* xt_c = xt_g + 8388608;
    ushort* wt_g = (ushort*)(ws + OFF_XF);
    ushort* wt_c = wt_g + 73728;

    // input transpose + weight re-layout (bf16)
    k_xt<<<dim3(128, 8, 2), 256, 0, stream>>>(in_g, in_c, xt_g, xt_c);
    k_wt<<<576, 256, 0, stream>>>((const float*)d_in[20], (const float*)d_in[21], wt_g, wt_c);

    // MFMA convs v2 (proven best)
    k_convm2<<<dim3(128, 8, 2), 256, 0, stream>>>(xt_g, xt_c, wt_g, wt_c, xqb);

    // pyramid pooling v2 (plane-packed)
    PoolPtrs pp;
    pp.src[0] = (const float*)d_in[3];  pp.src[1] = (const float*)d_in[9];  pp.src[2] = (const float*)d_in[15];
    pp.src[3] = (const float*)d_in[2];  pp.src[4] = (const float*)d_in[8];  pp.src[5] = (const float*)d_in[14];
    k_pool2<<<2048, 256, 66560, stream>>>(pp, ws);

    // weight precomputes
    k_pkw<<<368, 256, 0, stream>>>((const float*)d_in[24], (const float*)d_in[25],
                                   (const float*)d_in[22], (const float*)d_in[23],
                                   (const float*)d_in[26], (const float*)d_in[27],
                                   (const float*)d_in[28], ws);

    // xk (bf16), xv (f32)
    KvPtrs kp;
    kp.k1[0] = (const float*)d_in[4];  kp.k1[1] = (const float*)d_in[10]; kp.k1[2] = (const float*)d_in[16];
    kp.k2[0] = (const float*)d_in[6];  kp.k2[1] = (const float*)d_in[12]; kp.k2[2] = (const float*)d_in[18];
    kp.v1[0] = (const float*)d_in[5];  kp.v1[1] = (const float*)d_in[11]; kp.v1[2] = (const float*)d_in[17];
    kp.v2[0] = (const float*)d_in[7];  kp.v2[1] = (const float*)d_in[13]; kp.v2[2] = (const float*)d_in[19];
    k_xkxv<<<5376, 256, 0, stream>>>(kp, ws);

    // MTb bf16
    k_mt<<<3072, 256, 0, stream>>>(ws);

    // fused MFMA attention v8 (cooperative xk staging) -> t-field bf16 + tanh bf16 + p/g partials
    k_attn8<<<dim3(128, 8, 2), 256, 0, stream>>>(ws, in_g, in_c);

    // attc combine
    k_attc<<<192, 64, 0, stream>>>(ws);

    // GN stats (split) + combine, final
    k_stats2<<<dim3(8, 8, 8), 256, 0, stream>>>(ws, (const float*)d_in[29]);
    k_mv<<<1, 64, 0, stream>>>(ws);
    k_final<<<4096, 256, 0, stream>>>(ws, (const float*)d_in[29], (const float*)d_in[30],
                                      (const float*)d_in[31], in_g, out);
}